// Round 15
// baseline (124.267 us; speedup 1.0000x reference)
//
#include <hip/hip_runtime.h>
#include <stdint.h>

typedef __attribute__((ext_vector_type(8))) short bh8;       // 8 x bf16 (4 VGPR)
typedef __attribute__((ext_vector_type(4))) float f32x4;
typedef __attribute__((ext_vector_type(4))) unsigned short u16x4;
typedef __attribute__((ext_vector_type(8))) unsigned short u16x8;
typedef __attribute__((ext_vector_type(2))) unsigned int u32x2;

#define DEVI static __device__ __forceinline__

constexpr int B_ = 2, S_ = 2048, D_ = 1024, H_ = 16, E_ = 64;

// workspace layout (elements of ushort/bf16)
constexpr size_t OFF_XB  = 0;                              // x as bf16 [B*S, D]
constexpr size_t OFF_WQT = OFF_XB  + (size_t)B_*S_*D_;     // WqT [H, E, D]  } contiguous
constexpr size_t OFF_WKT = OFF_WQT + (size_t)H_*E_*D_;     // WkT [H, E, D]  } = one
constexpr size_t OFF_WVT = OFF_WKT + (size_t)H_*E_*D_;     // WvT [H, E, D]  } [3072,1024]
constexpr size_t OFF_WOT = OFF_WVT + (size_t)H_*E_*D_;     // WoT [D, D]
constexpr size_t OFF_Q   = OFF_WOT + (size_t)D_*D_;        // Q^T [B*H, E, S] (pre-scaled by 0.125*log2e)
constexpr size_t OFF_K   = OFF_Q   + (size_t)B_*H_*S_*E_;  // [B*H, S, E]
constexpr size_t OFF_VT  = OFF_K   + (size_t)B_*H_*S_*E_;  // [B*H, E, S]
constexpr size_t OFF_O   = OFF_VT  + (size_t)B_*H_*S_*E_;  // attn out concat [B*S, D]

DEVI unsigned short f2bf(float f) {
    union { float f; unsigned u; } v; v.f = f;
    unsigned u = v.u;
    return (unsigned short)((u + 0x7fffu + ((u >> 16) & 1u)) >> 16);
}

DEVI unsigned cvt_pk_bf16(float lo, float hi) {   // packs {lo,hi} -> 2 bf16 in one u32
    unsigned r;
    asm("v_cvt_pk_bf16_f32 %0, %1, %2" : "=v"(r) : "v"(lo), "v"(hi));
    return r;
}

DEVI void gload16(const void* g, void* l) {
    __builtin_amdgcn_global_load_lds(
        (const __attribute__((address_space(1))) unsigned int*)g,
        (__attribute__((address_space(3))) unsigned int*)l, 16, 0, 0);
}

DEVI f32x4 mfma16(bh8 a, bh8 b, f32x4 c) {
    return __builtin_amdgcn_mfma_f32_16x16x32_bf16(a, b, c, 0, 0, 0);
}

// counted-vmcnt barrier: prefetched loads stay in flight across the barrier.
template<int N> DEVI void vm_barrier() {
    asm volatile("s_waitcnt vmcnt(%0)" :: "i"(N) : "memory");
    __builtin_amdgcn_s_barrier();
    __builtin_amdgcn_sched_barrier(0);
}
DEVI void post_barrier() {
    __builtin_amdgcn_sched_barrier(0);
    __builtin_amdgcn_s_barrier();
    __builtin_amdgcn_sched_barrier(0);
}

// ---------------- prep: x -> bf16 ----------------
__global__ __launch_bounds__(256) void k_convert_x(const float* __restrict__ x,
                                                   unsigned short* __restrict__ ws) {
    const int i = blockIdx.x * 256 + threadIdx.x;   // one float4 each; n4 = 1048576
    const float4 v = ((const float4*)x)[i];
    u16x4 o = { f2bf(v.x), f2bf(v.y), f2bf(v.z), f2bf(v.w) };
    *(u16x4*)(ws + OFF_XB + (size_t)i * 4) = o;
}

// ---------------- prep: weights -> bf16, transposed ----------------
__global__ __launch_bounds__(256) void k_transpose_w(const float* __restrict__ Wq,
                                                     const float* __restrict__ Wk,
                                                     const float* __restrict__ Wv,
                                                     const float* __restrict__ Wo,
                                                     unsigned short* __restrict__ ws) {
    const int xi = blockIdx.x;   // 0..255
    const int z  = blockIdx.y;   // 0..3
    const int t  = threadIdx.x;
    __shared__ __align__(16) unsigned short tile[64][72];

    const float* src; unsigned short* dst;
    int inCols, inBase, outBase;
    if (z < 3) {
        src = (z == 0) ? Wq : (z == 1) ? Wk : Wv;
        dst = ws + ((z == 0) ? OFF_WQT : (z == 1) ? OFF_WKT : OFF_WVT);
        inCols = 64;
        inBase = xi * 64 * 64;
        const int h = xi >> 4, dt = xi & 15;
        outBase = h * 65536 + dt * 64;
    } else {
        src = Wo; dst = ws + OFF_WOT;
        inCols = 1024;
        const int et = xi >> 4, dt = xi & 15;
        inBase  = (dt * 64) * 1024 + et * 64;
        outBase = (et * 64) * 1024 + dt * 64;
    }
#pragma unroll
    for (int v = 0; v < 4; ++v) {
        const int flat = v * 256 + t;
        const int i = flat >> 4, j4 = (flat & 15) * 4;
        const float4 val = *(const float4*)(src + inBase + i * inCols + j4);
        tile[i][j4 + 0] = f2bf(val.x);
        tile[i][j4 + 1] = f2bf(val.y);
        tile[i][j4 + 2] = f2bf(val.z);
        tile[i][j4 + 3] = f2bf(val.w);
    }
    __syncthreads();
    const int j = t >> 2, iseg = (t & 3) * 16;
    u16x8 p0, p1;
#pragma unroll
    for (int u = 0; u < 8; ++u) p0[u] = tile[iseg + u][j];
#pragma unroll
    for (int u = 0; u < 8; ++u) p1[u] = tile[iseg + 8 + u][j];
    *(u16x8*)(dst + outBase + (size_t)j * 1024 + iseg)     = p0;
    *(u16x8*)(dst + outBase + (size_t)j * 1024 + iseg + 8) = p1;
}

// ================= qkv 256x256 8-phase machinery =================
DEVI void qkv_stA(const unsigned short* Ap, unsigned short* lds, int kt, int mh, int ks,
                  int lane, int w, int lr, int lg) {
    const int b = kt & 1;
    const int mfrag = (w >> 2) * 8 + mh * 4 + (w & 3);
    gload16(Ap + (size_t)(mfrag * 16 + lr) * D_ + kt * 64 + ks * 32 + lg * 8,
            lds + b * 16384 + (mfrag * 2 + ks) * 512 + lane * 8);
}
DEVI void qkv_stB(const unsigned short* Bp, unsigned short* lds, int kt, int ks,
                  int lane, int w, int lr, int lg) {
    const int b = kt & 1;
#pragma unroll
    for (int u = 0; u < 2; ++u) {
        const int nfrag = w * 2 + u;
        gload16(Bp + (size_t)(nfrag * 16 + lr) * D_ + kt * 64 + ks * 32 + lg * 8,
                lds + 32768 + b * 16384 + (nfrag * 2 + ks) * 512 + lane * 8);
    }
}
DEVI bh8 qkv_ldA(const unsigned short* lds, int b, int mfrag, int ks, int lane) {
    return *(const bh8*)(lds + b * 16384 + (mfrag * 2 + ks) * 512 + lane * 8);
}
DEVI bh8 qkv_ldB(const unsigned short* lds, int b, int nfrag, int ks, int lane) {
    return *(const bh8*)(lds + 32768 + b * 16384 + (nfrag * 2 + ks) * 512 + lane * 8);
}

template<int V0, int V1, int V2, int V3, bool S0, bool S123>
DEVI void qkv_ktile(int kt, const unsigned short* Ap, const unsigned short* Bp,
                    unsigned short* lds, int lane, int w, int lr, int lg,
                    int wm, int wn, f32x4 (&acc)[8][4]) {
    const int b = kt & 1;
    bh8 af[4], bf[4];
    // ---- phase 0: quad(mh=0, ks=0); stage A(1,1) of kt+1 ----
    vm_barrier<V0>();
#pragma unroll
    for (int n = 0; n < 4; ++n) bf[n] = qkv_ldB(lds, b, wn * 4 + n, 0, lane);
#pragma unroll
    for (int q = 0; q < 4; ++q) af[q] = qkv_ldA(lds, b, wm * 8 + q, 0, lane);
    if (S0) qkv_stA(Ap, lds, kt + 1, 1, 1, lane, w, lr, lg);
    __builtin_amdgcn_s_setprio(1);
#pragma unroll
    for (int q = 0; q < 4; ++q)
#pragma unroll
        for (int n = 0; n < 4; ++n) acc[q][n] = mfma16(af[q], bf[n], acc[q][n]);
    __builtin_amdgcn_s_setprio(0);
    __builtin_amdgcn_sched_barrier(0);
    // ---- phase 1: quad(1,0); stage A(0,0)+B(ks0) of kt+2 ----
    vm_barrier<V1>();
#pragma unroll
    for (int q = 0; q < 4; ++q) af[q] = qkv_ldA(lds, b, wm * 8 + 4 + q, 0, lane);
    if (S123) {
        qkv_stA(Ap, lds, kt + 2, 0, 0, lane, w, lr, lg);
        qkv_stB(Bp, lds, kt + 2, 0, lane, w, lr, lg);
    }
    __builtin_amdgcn_s_setprio(1);
#pragma unroll
    for (int q = 0; q < 4; ++q)
#pragma unroll
        for (int n = 0; n < 4; ++n) acc[4 + q][n] = mfma16(af[q], bf[n], acc[4 + q][n]);
    __builtin_amdgcn_s_setprio(0);
    __builtin_amdgcn_sched_barrier(0);
    // ---- phase 2: quad(0,1); stage A(1,0) of kt+2 ----
    vm_barrier<V2>();
#pragma unroll
    for (int n = 0; n < 4; ++n) bf[n] = qkv_ldB(lds, b, wn * 4 + n, 1, lane);
#pragma unroll
    for (int q = 0; q < 4; ++q) af[q] = qkv_ldA(lds, b, wm * 8 + q, 1, lane);
    if (S123) qkv_stA(Ap, lds, kt + 2, 1, 0, lane, w, lr, lg);
    __builtin_amdgcn_s_setprio(1);
#pragma unroll
    for (int q = 0; q < 4; ++q)
#pragma unroll
        for (int n = 0; n < 4; ++n) acc[q][n] = mfma16(af[q], bf[n], acc[q][n]);
    __builtin_amdgcn_s_setprio(0);
    __builtin_amdgcn_sched_barrier(0);
    // ---- phase 3: quad(1,1); stage A(0,1)+B(ks1) of kt+2 ----
    vm_barrier<V3>();
#pragma unroll
    for (int q = 0; q < 4; ++q) af[q] = qkv_ldA(lds, b, wm * 8 + 4 + q, 1, lane);
    if (S123) {
        qkv_stA(Ap, lds, kt + 2, 0, 1, lane, w, lr, lg);
        qkv_stB(Bp, lds, kt + 2, 1, lane, w, lr, lg);
    }
    __builtin_amdgcn_s_setprio(1);
#pragma unroll
    for (int q = 0; q < 4; ++q)
#pragma unroll
        for (int n = 0; n < 4; ++n) acc[4 + q][n] = mfma16(af[q], bf[n], acc[4 + q][n]);
    __builtin_amdgcn_s_setprio(0);
    __builtin_amdgcn_sched_barrier(0);
}

// ---------------- fused QKV projection: 256x256 tiles, 8 waves, 8-phase ----------------
__global__ __launch_bounds__(512, 2) void k_qkv(unsigned short* __restrict__ ws,
                                                const float* __restrict__ bq,
                                                const float* __restrict__ bk,
                                                const float* __restrict__ bv) {
    const int flat  = blockIdx.x;                   // 0..191
    const int idx   = flat >> 3;                    // 0..23
    const int stile = (flat & 7) * 2 + (idx & 1);   // 0..15 (256 rows each)
    const int ntile = idx >> 1;                     // 0..11 (256 cols each of 3072)
    const unsigned short* Ap = ws + OFF_XB  + (size_t)stile * 256 * D_;
    const unsigned short* Bp = ws + OFF_WQT + (size_t)ntile * 256 * D_;

    __shared__ __align__(16) unsigned short lds[65536];   // 128 KB
    const int tid = threadIdx.x, lane = tid & 63, w = tid >> 6;
    const int lr = lane & 15, lg = lane >> 4;
    const int wm = w >> 2, wn = w & 3;               // wave tile: rows wm*128, cols wn*64

    f32x4 acc[8][4];
#pragma unroll
    for (int i = 0; i < 8; ++i)
#pragma unroll
        for (int j = 0; j < 4; ++j) acc[i][j] = (f32x4){0.f, 0.f, 0.f, 0.f};

    // prologue: kt0 full (8) + kt1 minus A(1,1) (7), in steady-state FIFO order
    qkv_stA(Ap, lds, 0, 0, 0, lane, w, lr, lg);
    qkv_stB(Bp, lds, 0, 0, lane, w, lr, lg);
    qkv_stA(Ap, lds, 0, 1, 0, lane, w, lr, lg);
    qkv_stA(Ap, lds, 0, 0, 1, lane, w, lr, lg);
    qkv_stB(Bp, lds, 0, 1, lane, w, lr, lg);
    qkv_stA(Ap, lds, 0, 1, 1, lane, w, lr, lg);
    qkv_stA(Ap, lds, 1, 0, 0, lane, w, lr, lg);
    qkv_stB(Bp, lds, 1, 0, lane, w, lr, lg);
    qkv_stA(Ap, lds, 1, 1, 0, lane, w, lr, lg);
    qkv_stA(Ap, lds, 1, 0, 1, lane, w, lr, lg);
    qkv_stB(Bp, lds, 1, 1, lane, w, lr, lg);

    for (int kt = 0; kt < 14; ++kt)
        qkv_ktile<12, 12, 12, 12, true, true>(kt, Ap, Bp, lds, lane, w, lr, lg, wm, wn, acc);
    qkv_ktile<12, 12, 9, 8, true, false>(14, Ap, Bp, lds, lane, w, lr, lg, wm, wn, acc);
    qkv_ktile<5, 4, 1, 0, false, false>(15, Ap, Bp, lds, lane, w, lr, lg, wm, wn, acc);

    // epilogue: wave writes one head's 64-col slab. c = ntile*4+wn in 0..47
    const int c = ntile * 4 + wn;
    const int mat = c >> 4, h = c & 15;
    const float* bias = ((mat == 0) ? bq : (mat == 1) ? bk : bv) + h * 64;
    const int bb = stile >> 3;                       // batch (256 | 2048, no straddle)
    const int bh = bb * H_ + h;
#pragma unroll
    for (int mf = 0; mf < 8; ++mf) {
        const int sl = ((stile * 256 + wm * 128 + mf * 16) & (S_ - 1)) + lg * 4;
#pragma unroll
        for (int nf = 0; nf < 4; ++nf) {
            const int e = nf * 16 + lr;
            const float bia = bias[e];
            if (mat == 0) {        // Q^T [BH][E][S], pre-scaled by 0.125*log2e
                u16x4 pk;
#pragma unroll
                for (int r = 0; r < 4; ++r)
                    pk[r] = f2bf((acc[mf][nf][r] + bia) * 0.1803368801f);
                *(u16x4*)(ws + OFF_Q + ((size_t)(bh * E_ + e)) * S_ + sl) = pk;
            } else if (mat == 2) { // V^T [BH][E][S]
                u16x4 pk;
#pragma unroll
                for (int r = 0; r < 4; ++r) pk[r] = f2bf(acc[mf][nf][r] + bia);
                *(u16x4*)(ws + OFF_VT + ((size_t)(bh * E_ + e)) * S_ + sl) = pk;
            } else {               // K [BH][S][E]
#pragma unroll
                for (int r = 0; r < 4; ++r)
                    ws[OFF_K + ((size_t)bh * S_ + sl + r) * E_ + e] =
                        f2bf(acc[mf][nf][r] + bia);
            }
        }
    }
}

// ---------------- GEMM mainloop: C(128x128) (oproj) ----------------
DEVI void gemm_tile_128x128(const unsigned short* __restrict__ A,
                            const unsigned short* __restrict__ Bw,
                            unsigned short* lds,
                            f32x4 acc[2][8]) {
    const int lane = threadIdx.x & 63;
    const int w    = threadIdx.x >> 6;
    const int lr = lane & 15, lg = lane >> 4;
    const unsigned short* a0 = A  + (size_t)((w * 2 + 0) * 16 + lr) * D_ + lg * 8;
    const unsigned short* a1 = A  + (size_t)((w * 2 + 1) * 16 + lr) * D_ + lg * 8;
    const unsigned short* b0 = Bw + (size_t)((w * 2 + 0) * 16 + lr) * D_ + lg * 8;
    const unsigned short* b1 = Bw + (size_t)((w * 2 + 1) * 16 + lr) * D_ + lg * 8;
    const int oA0 = (w * 2 + 0) * 512, oA1 = (w * 2 + 1) * 512;
    const int oB0 = 4096 + oA0,        oB1 = 4096 + oA1;

    auto stage = [&](int ks, int bufi) {
        unsigned short* base = lds + bufi * 8192;
        gload16(a0 + ks * 32, base + oA0);
        gload16(a1 + ks * 32, base + oA1);
        gload16(b0 + ks * 32, base + oB0);
        gload16(b1 + ks * 32, base + oB1);
    };

    stage(0, 0); stage(1, 1);
    for (int ks = 0; ks < 32; ++ks) {
        if (ks < 31) vm_barrier<4>();
        else         vm_barrier<0>();
        if (ks + 2 < 32) stage(ks + 2, (ks + 2) % 3);
        const unsigned short* base = lds + (ks % 3) * 8192;
        bh8 af0 = *(const bh8*)(base + (w * 2 + 0) * 512 + lane * 8);
        bh8 af1 = *(const bh8*)(base + (w * 2 + 1) * 512 + lane * 8);
#pragma unroll
        for (int nt = 0; nt < 8; ++nt) {
            bh8 bf = *(const bh8*)(base + 4096 + nt * 512 + lane * 8);
            acc[0][nt] = mfma16(af0, bf, acc[0][nt]);
            acc[1][nt] = mfma16(af1, bf, acc[1][nt]);
        }
        __builtin_amdgcn_sched_barrier(0);
    }
}

// ---------------- flash attention (causal), swapped-QK^T, 32 q-rows/wave ----------------
// QBLK=128 (4 waves x 32 rows), KVBLK=64. Each K/V LDS fragment read feeds 2 MFMAs
// (was 1) -> K/V LDS read bytes per q-row halve. LDS 48 KB -> 3 blocks/CU.
__global__ __launch_bounds__(256, 3) void k_attn(unsigned short* __restrict__ ws) {
    const int flat = blockIdx.x;          // 0..511
    const int j    = flat & 31;
    const int qt2  = 15 - (flat >> 5);    // heavy tiles first (128 q rows each)
    const int bh   = (j & 7) * 4 + (j >> 3);
    const int lane = threadIdx.x & 63, w = threadIdx.x >> 6;
    const int lr = lane & 15, lg = lane >> 4;
    const unsigned short* Qp = ws + OFF_Q  + (size_t)bh * E_ * S_;   // Q^T [E][S]
    const unsigned short* Kp = ws + OFF_K  + (size_t)bh * S_ * E_;
    const unsigned short* Vp = ws + OFF_VT + (size_t)bh * E_ * S_;
    __shared__ __align__(16) unsigned short ldsK[2][8 * 512];
    __shared__ __align__(16) unsigned short ldsV[2][8 * 512];
    __shared__ __align__(16) unsigned short ldsP[4 * 2048];   // per-wave 2 x (64k x 16q)

    const int qbase = qt2 * 128 + w * 32;   // this wave's 32 q rows
    bh8 qf[2][2];
#pragma unroll
    for (int mq = 0; mq < 2; ++mq)
#pragma unroll
        for (int kg = 0; kg < 2; ++kg) {
            bh8 t;
#pragma unroll
            for (int i = 0; i < 8; ++i)
                t[i] = (short)Qp[(size_t)(kg * 32 + lg * 8 + i) * S_ + qbase + mq * 16 + lr];
            qf[mq][kg] = t;
        }

    f32x4 o[2][4];
    float m[2] = {-3.0e38f, -3.0e38f}, l[2] = {0.f, 0.f};   // per-lane state for q = lr
#pragma unroll
    for (int mq = 0; mq < 2; ++mq)
#pragma unroll
        for (int i = 0; i < 4; ++i) o[mq][i] = (f32x4){0.f, 0.f, 0.f, 0.f};

    auto stage = [&](int kt, int bufi) {
        const int sk0 = kt * 64;
#pragma unroll
        for (int u = 0; u < 2; ++u) {
            const int blk = w * 2 + u;
            const int ct = blk >> 1, kg = blk & 1;
            gload16(Kp + (size_t)(sk0 + ct * 16 + lr) * E_ + kg * 32 + lg * 8,
                    &ldsK[bufi][blk * 512]);
            gload16(Vp + (size_t)(ct * 16 + lr) * S_ + sk0 + kg * 32 + lg * 8,
                    &ldsV[bufi][blk * 512]);
        }
    };

    unsigned short* Pw = ldsP + w * 2048;
    const int nkt = 2 * qt2 + 2;

    stage(0, 0);
    if (nkt > 1) stage(1, 1);

    for (int kt = 0; kt < nkt; ++kt) {
        if (kt + 1 < nkt) vm_barrier<4>();
        else              vm_barrier<0>();
        const int cur = kt & 1;
        const unsigned short* Kc = ldsK[cur];
        const unsigned short* Vc = ldsV[cur];

        // S^T = K Q^T: sc[mq][ct][r] = score[s_k = kt*64+ct*16+lg*4+r][q = mq*16+lr]
        f32x4 sc[2][4];
#pragma unroll
        for (int mq = 0; mq < 2; ++mq)
#pragma unroll
            for (int ct = 0; ct < 4; ++ct) sc[mq][ct] = (f32x4){0.f, 0.f, 0.f, 0.f};
#pragma unroll
        for (int ct = 0; ct < 4; ++ct)
#pragma unroll
            for (int kg = 0; kg < 2; ++kg) {
                bh8 kf = *(const bh8*)(Kc + (ct * 2 + kg) * 512 + lane * 8);   // 1 read, 2 MFMA
                sc[0][ct] = mfma16(kf, qf[0][kg], sc[0][ct]);
                sc[1][ct] = mfma16(kf, qf[1][kg], sc[1][ct]);
            }
        // causal mask: only the last two tiles (kt >= 2*qt2) overlap the q range
        if (kt >= 2 * qt2) {
            const int dq = qt2 * 128 - kt * 64;
#pragma unroll
            for (int mq = 0; mq < 2; ++mq) {
                const int qo = w * 32 + mq * 16 + lr + dq;
#pragma unroll
                for (int ct = 0; ct < 4; ++ct) {
                    const int skl = ct * 16 + lg * 4;
#pragma unroll
                    for (int r = 0; r < 4; ++r)
                        if (skl + r > qo) sc[mq][ct][r] = -3.0e38f;
                }
            }
        }
        // column (q) max per mq: 15 in-lane fmax + 2 shfl
        float mx[2];
#pragma unroll
        for (int mq = 0; mq < 2; ++mq) {
            float v = fmaxf(fmaxf(sc[mq][0][0], sc[mq][0][1]),
                            fmaxf(sc[mq][0][2], sc[mq][0][3]));
#pragma unroll
            for (int ct = 1; ct < 4; ++ct)
                v = fmaxf(v, fmaxf(fmaxf(sc[mq][ct][0], sc[mq][ct][1]),
                                   fmaxf(sc[mq][ct][2], sc[mq][ct][3])));
            v = fmaxf(v, __shfl_xor(v, 16, 64));
            mx[mq] = fmaxf(v, __shfl_xor(v, 32, 64));
        }
        // defer-max (T13): rescale only when max grew by > 8 (log2 domain)
        const bool need0 = mx[0] > m[0] + 8.0f, need1 = mx[1] > m[1] + 8.0f;
        if (__any(need0 | need1)) {
#pragma unroll
            for (int mq = 0; mq < 2; ++mq) {
                const bool nd = mq == 0 ? need0 : need1;
                const float mn = nd ? mx[mq] : m[mq];
                const float sf = __builtin_amdgcn_exp2f(m[mq] - mn);   // 1.0 when !nd
                m[mq] = mn;
                l[mq] *= sf;
#pragma unroll
                for (int r = 0; r < 4; ++r) {
                    const float sfq = __shfl(sf, (lane & 48) + lg * 4 + r, 64);
#pragma unroll
                    for (int et = 0; et < 4; ++et) o[mq][et][r] *= sfq;
                }
            }
        }
        // P = exp2(S - m), partial sums; pack P and write A-frag order
#pragma unroll
        for (int mq = 0; mq < 2; ++mq) {
            float rs = 0.f;
#pragma unroll
            for (int ct = 0; ct < 4; ++ct)
#pragma unroll
                for (int r = 0; r < 4; ++r) {
                    float p = __builtin_amdgcn_exp2f(sc[mq][ct][r] - m[mq]);
                    sc[mq][ct][r] = p;
                    rs += p;
                }
            rs += __shfl_xor(rs, 16, 64);
            rs += __shfl_xor(rs, 32, 64);
            l[mq] += rs;
#pragma unroll
            for (int ct = 0; ct < 4; ++ct) {
                u32x2 pk = { cvt_pk_bf16(sc[mq][ct][0], sc[mq][ct][1]),
                             cvt_pk_bf16(sc[mq][ct][2], sc[mq][ct][3]) };
                const int addr = mq * 1024 + (ct >> 1) * 512 +
                                 ((((ct & 1) * 2) + (lg >> 1)) * 16 + lr) * 8 + (lg & 1) * 4;
                *(u32x2*)(Pw + addr) = pk;
            }
        }
        // O += P V  (wave-private P; lgkm-ordered, no barrier). 1 vf read, 2 MFMA.
#pragma unroll
        for (int skg = 0; skg < 2; ++skg) {
            bh8 pf0 = *(const bh8*)(Pw + 0 * 1024 + skg * 512 + lane * 8);
            bh8 pf1 = *(const bh8*)(Pw + 1 * 1024 + skg * 512 + lane * 8);
#pragma unroll
            for (int et = 0; et < 4; ++et) {
                bh8 vf = *(const bh8*)(Vc + (et * 2 + skg) * 512 + lane * 8);
                o[0][et] = mfma16(pf0, vf, o[0][et]);
                o[1][et] = mfma16(pf1, vf, o[1][et]);
            }
        }
        post_barrier();
        if (kt + 2 < nkt) stage(kt + 2, cur);
    }
    // epilogue: O/l -> concat layout [B,S,H*64]; l lives at lane with lr = q
    const int b = bh >> 4, hh = bh & 15;
#pragma unroll
    for (int mq = 0; mq < 2; ++mq)
#pragma unroll
        for (int r = 0; r < 4; ++r) {
            const float lq = __shfl(l[mq], (lane & 48) + lg * 4 + r, 64);
            const float inv = 1.0f / lq;
            const int s = qbase + mq * 16 + lg * 4 + r;
#pragma unroll
            for (int et = 0; et < 4; ++et)
                ws[OFF_O + ((size_t)(b * S_ + s)) * D_ + hh * E_ + et * 16 + lr] =
                    f2bf(o[mq][et][r] * inv);
        }
}

// ---------------- output projection: C[4096,1024] = O * WoT^T ----------------
__global__ __launch_bounds__(256, 3) void k_oproj(const unsigned short* __restrict__ ws,
                                                  const float* __restrict__ bo,
                                                  float* __restrict__ out) {
    const int flat  = blockIdx.x;          // 0..255
    const int idx   = flat >> 3;           // 0..31
    const int stile = (flat & 7) * 4 + (idx & 3);   // 0..31
    const int ntile = idx >> 2;            // 0..7 (128 cols each)
    const unsigned short* A  = ws + OFF_O   + (size_t)stile * 128 * D_;
    const unsigned short* Bw = ws + OFF_WOT + (size_t)ntile * 128 * D_;
    __shared__ __align__(16) unsigned short lds[3 * 8192];
    f32x4 acc[2][8];
#pragma unroll
    for (int i = 0; i < 2; ++i)
#pragma unroll
        for (int j = 0; j < 8; ++j) acc[i][j] = (f32x4){0.f, 0.f, 0.f, 0.f};

    gemm_tile_128x128(A, Bw, lds, acc);

    const int lane = threadIdx.x & 63, w = threadIdx.x >> 6;
    const int lr = lane & 15, lg = lane >> 4;
    const int r0 = stile * 128 + w * 32;
#pragma unroll
    for (int mt = 0; mt < 2; ++mt)
#pragma unroll
        for (int nt = 0; nt < 8; ++nt) {
            const int e = ntile * 128 + nt * 16 + lr;
            const float bia = bo[e];
#pragma unroll
            for (int r = 0; r < 4; ++r)
                out[(size_t)(r0 + mt * 16 + lg * 4 + r) * D_ + e] = acc[mt][nt][r] + bia;
        }
}

extern "C" void kernel_launch(void* const* d_in, const int* in_sizes, int n_in,
                              void* d_out, int out_size, void* d_ws, size_t ws_size,
                              hipStream_t stream) {
    const float* x  = (const float*)d_in[0];
    const float* Wq = (const float*)d_in[1];
    const float* bq = (const float*)d_in[2];
    const float* Wk = (const float*)d_in[3];
    const float* bk = (const float*)d_in[4];
    const float* Wv = (const float*)d_in[5];
    const float* bv = (const float*)d_in[6];
    const float* Wo = (const float*)d_in[7];
    const float* bo = (const float*)d_in[8];
    float* out = (float*)d_out;
    unsigned short* ws = (unsigned short*)d_ws;

    k_convert_x<<<dim3((B_ * S_ * D_) / 4 / 256), 256, 0, stream>>>(x, ws);
    k_transpose_w<<<dim3(256, 4), 256, 0, stream>>>(Wq, Wk, Wv, Wo, ws);
    k_qkv<<<dim3(192), 512, 0, stream>>>(ws, bq, bk, bv);
    k_attn<<<dim3(512), 256, 0, stream>>>(ws);
    k_oproj<<<dim3(256), 256, 0, stream>>>(ws, bo, out);
}

// Round 17
// 116.817 us; speedup vs baseline: 1.0638x; 1.0638x over previous
//
#include <hip/hip_runtime.h>
#include <stdint.h>

typedef __attribute__((ext_vector_type(8))) short bh8;       // 8 x bf16 (4 VGPR)
typedef __attribute__((ext_vector_type(4))) float f32x4;
typedef __attribute__((ext_vector_type(4))) unsigned short u16x4;
typedef __attribute__((ext_vector_type(8))) unsigned short u16x8;
typedef __attribute__((ext_vector_type(2))) unsigned int u32x2;

#define DEVI static __device__ __forceinline__

constexpr int B_ = 2, S_ = 2048, D_ = 1024, H_ = 16, E_ = 64;

// workspace layout (elements of ushort/bf16)
constexpr size_t OFF_XB  = 0;                              // x as bf16 [B*S, D]
constexpr size_t OFF_WQT = OFF_XB  + (size_t)B_*S_*D_;     // WqT [H, E, D]  } contiguous
constexpr size_t OFF_WKT = OFF_WQT + (size_t)H_*E_*D_;     // WkT [H, E, D]  } = one
constexpr size_t OFF_WVT = OFF_WKT + (size_t)H_*E_*D_;     // WvT [H, E, D]  } [3072,1024]
constexpr size_t OFF_WOT = OFF_WVT + (size_t)H_*E_*D_;     // WoT [D, D]
constexpr size_t OFF_Q   = OFF_WOT + (size_t)D_*D_;        // Q^T [B*H, E, S] (pre-scaled by 0.125*log2e)
constexpr size_t OFF_K   = OFF_Q   + (size_t)B_*H_*S_*E_;  // [B*H, S, E]
constexpr size_t OFF_VT  = OFF_K   + (size_t)B_*H_*S_*E_;  // [B*H, E, S]
constexpr size_t OFF_O   = OFF_VT  + (size_t)B_*H_*S_*E_;  // attn out concat [B*S, D]

DEVI unsigned short f2bf(float f) {
    union { float f; unsigned u; } v; v.f = f;
    unsigned u = v.u;
    return (unsigned short)((u + 0x7fffu + ((u >> 16) & 1u)) >> 16);
}

DEVI unsigned cvt_pk_bf16(float lo, float hi) {   // packs {lo,hi} -> 2 bf16 in one u32
    unsigned r;
    asm("v_cvt_pk_bf16_f32 %0, %1, %2" : "=v"(r) : "v"(lo), "v"(hi));
    return r;
}

DEVI void gload16(const void* g, void* l) {
    __builtin_amdgcn_global_load_lds(
        (const __attribute__((address_space(1))) unsigned int*)g,
        (__attribute__((address_space(3))) unsigned int*)l, 16, 0, 0);
}

DEVI f32x4 mfma16(bh8 a, bh8 b, f32x4 c) {
    return __builtin_amdgcn_mfma_f32_16x16x32_bf16(a, b, c, 0, 0, 0);
}

// counted-vmcnt barrier: prefetched loads stay in flight across the barrier.
template<int N> DEVI void vm_barrier() {
    asm volatile("s_waitcnt vmcnt(%0)" :: "i"(N) : "memory");
    __builtin_amdgcn_s_barrier();
    __builtin_amdgcn_sched_barrier(0);
}
DEVI void post_barrier() {
    __builtin_amdgcn_sched_barrier(0);
    __builtin_amdgcn_s_barrier();
    __builtin_amdgcn_sched_barrier(0);
}

// ---------------- prep (fused): x -> bf16  AND  weights -> bf16 transposed ----------------
// blocks 0..4095: convert x (one float4/thread; 4096*256 = 1048576 float4 = all of x).
// blocks 4096..5119: transpose weights. Outputs disjoint; branch is block-uniform.
__global__ __launch_bounds__(256) void k_prep(const float* __restrict__ x,
                                              const float* __restrict__ Wq,
                                              const float* __restrict__ Wk,
                                              const float* __restrict__ Wv,
                                              const float* __restrict__ Wo,
                                              unsigned short* __restrict__ ws) {
    const int bid = blockIdx.x;
    const int t   = threadIdx.x;
    if (bid < 4096) {
        const int i = bid * 256 + t;
        const float4 v = ((const float4*)x)[i];
        u16x4 o = { f2bf(v.x), f2bf(v.y), f2bf(v.z), f2bf(v.w) };
        *(u16x4*)(ws + OFF_XB + (size_t)i * 4) = o;
        return;
    }
    const int xi = (bid - 4096) & 255;   // 0..255
    const int z  = (bid - 4096) >> 8;    // 0..3
    __shared__ __align__(16) unsigned short tile[64][72];

    const float* src; unsigned short* dst;
    int inCols, inBase, outBase;
    if (z < 3) {
        src = (z == 0) ? Wq : (z == 1) ? Wk : Wv;
        dst = ws + ((z == 0) ? OFF_WQT : (z == 1) ? OFF_WKT : OFF_WVT);
        inCols = 64;
        inBase = xi * 64 * 64;
        const int h = xi >> 4, dt = xi & 15;
        outBase = h * 65536 + dt * 64;
    } else {
        src = Wo; dst = ws + OFF_WOT;
        inCols = 1024;
        const int et = xi >> 4, dt = xi & 15;
        inBase  = (dt * 64) * 1024 + et * 64;
        outBase = (et * 64) * 1024 + dt * 64;
    }
#pragma unroll
    for (int v = 0; v < 4; ++v) {
        const int flat = v * 256 + t;
        const int i = flat >> 4, j4 = (flat & 15) * 4;
        const float4 val = *(const float4*)(src + inBase + i * inCols + j4);
        tile[i][j4 + 0] = f2bf(val.x);
        tile[i][j4 + 1] = f2bf(val.y);
        tile[i][j4 + 2] = f2bf(val.z);
        tile[i][j4 + 3] = f2bf(val.w);
    }
    __syncthreads();
    const int j = t >> 2, iseg = (t & 3) * 16;
    u16x8 p0, p1;
#pragma unroll
    for (int u = 0; u < 8; ++u) p0[u] = tile[iseg + u][j];
#pragma unroll
    for (int u = 0; u < 8; ++u) p1[u] = tile[iseg + 8 + u][j];
    *(u16x8*)(dst + outBase + (size_t)j * 1024 + iseg)     = p0;
    *(u16x8*)(dst + outBase + (size_t)j * 1024 + iseg + 8) = p1;
}

// ================= qkv 256x256 8-phase machinery =================
DEVI void qkv_stA(const unsigned short* Ap, unsigned short* lds, int kt, int mh, int ks,
                  int lane, int w, int lr, int lg) {
    const int b = kt & 1;
    const int mfrag = (w >> 2) * 8 + mh * 4 + (w & 3);
    gload16(Ap + (size_t)(mfrag * 16 + lr) * D_ + kt * 64 + ks * 32 + lg * 8,
            lds + b * 16384 + (mfrag * 2 + ks) * 512 + lane * 8);
}
DEVI void qkv_stB(const unsigned short* Bp, unsigned short* lds, int kt, int ks,
                  int lane, int w, int lr, int lg) {
    const int b = kt & 1;
#pragma unroll
    for (int u = 0; u < 2; ++u) {
        const int nfrag = w * 2 + u;
        gload16(Bp + (size_t)(nfrag * 16 + lr) * D_ + kt * 64 + ks * 32 + lg * 8,
                lds + 32768 + b * 16384 + (nfrag * 2 + ks) * 512 + lane * 8);
    }
}
DEVI bh8 qkv_ldA(const unsigned short* lds, int b, int mfrag, int ks, int lane) {
    return *(const bh8*)(lds + b * 16384 + (mfrag * 2 + ks) * 512 + lane * 8);
}
DEVI bh8 qkv_ldB(const unsigned short* lds, int b, int nfrag, int ks, int lane) {
    return *(const bh8*)(lds + 32768 + b * 16384 + (nfrag * 2 + ks) * 512 + lane * 8);
}

template<int V0, int V1, int V2, int V3, bool S0, bool S123>
DEVI void qkv_ktile(int kt, const unsigned short* Ap, const unsigned short* Bp,
                    unsigned short* lds, int lane, int w, int lr, int lg,
                    int wm, int wn, f32x4 (&acc)[8][4]) {
    const int b = kt & 1;
    bh8 af[4], bf[4];
    // ---- phase 0: quad(mh=0, ks=0); stage A(1,1) of kt+1 ----
    vm_barrier<V0>();
#pragma unroll
    for (int n = 0; n < 4; ++n) bf[n] = qkv_ldB(lds, b, wn * 4 + n, 0, lane);
#pragma unroll
    for (int q = 0; q < 4; ++q) af[q] = qkv_ldA(lds, b, wm * 8 + q, 0, lane);
    if (S0) qkv_stA(Ap, lds, kt + 1, 1, 1, lane, w, lr, lg);
    __builtin_amdgcn_s_setprio(1);
#pragma unroll
    for (int q = 0; q < 4; ++q)
#pragma unroll
        for (int n = 0; n < 4; ++n) acc[q][n] = mfma16(af[q], bf[n], acc[q][n]);
    __builtin_amdgcn_s_setprio(0);
    __builtin_amdgcn_sched_barrier(0);
    // ---- phase 1: quad(1,0); stage A(0,0)+B(ks0) of kt+2 ----
    vm_barrier<V1>();
#pragma unroll
    for (int q = 0; q < 4; ++q) af[q] = qkv_ldA(lds, b, wm * 8 + 4 + q, 0, lane);
    if (S123) {
        qkv_stA(Ap, lds, kt + 2, 0, 0, lane, w, lr, lg);
        qkv_stB(Bp, lds, kt + 2, 0, lane, w, lr, lg);
    }
    __builtin_amdgcn_s_setprio(1);
#pragma unroll
    for (int q = 0; q < 4; ++q)
#pragma unroll
        for (int n = 0; n < 4; ++n) acc[4 + q][n] = mfma16(af[q], bf[n], acc[4 + q][n]);
    __builtin_amdgcn_s_setprio(0);
    __builtin_amdgcn_sched_barrier(0);
    // ---- phase 2: quad(0,1); stage A(1,0) of kt+2 ----
    vm_barrier<V2>();
#pragma unroll
    for (int n = 0; n < 4; ++n) bf[n] = qkv_ldB(lds, b, wn * 4 + n, 1, lane);
#pragma unroll
    for (int q = 0; q < 4; ++q) af[q] = qkv_ldA(lds, b, wm * 8 + q, 1, lane);
    if (S123) qkv_stA(Ap, lds, kt + 2, 1, 0, lane, w, lr, lg);
    __builtin_amdgcn_s_setprio(1);
#pragma unroll
    for (int q = 0; q < 4; ++q)
#pragma unroll
        for (int n = 0; n < 4; ++n) acc[q][n] = mfma16(af[q], bf[n], acc[q][n]);
    __builtin_amdgcn_s_setprio(0);
    __builtin_amdgcn_sched_barrier(0);
    // ---- phase 3: quad(1,1); stage A(0,1)+B(ks1) of kt+2 ----
    vm_barrier<V3>();
#pragma unroll
    for (int q = 0; q < 4; ++q) af[q] = qkv_ldA(lds, b, wm * 8 + 4 + q, 1, lane);
    if (S123) {
        qkv_stA(Ap, lds, kt + 2, 0, 1, lane, w, lr, lg);
        qkv_stB(Bp, lds, kt + 2, 1, lane, w, lr, lg);
    }
    __builtin_amdgcn_s_setprio(1);
#pragma unroll
    for (int q = 0; q < 4; ++q)
#pragma unroll
        for (int n = 0; n < 4; ++n) acc[4 + q][n] = mfma16(af[q], bf[n], acc[4 + q][n]);
    __builtin_amdgcn_s_setprio(0);
    __builtin_amdgcn_sched_barrier(0);
}

// ---------------- fused QKV projection: 256x256 tiles, 8 waves, 8-phase ----------------
__global__ __launch_bounds__(512, 2) void k_qkv(unsigned short* __restrict__ ws,
                                                const float* __restrict__ bq,
                                                const float* __restrict__ bk,
                                                const float* __restrict__ bv) {
    const int flat  = blockIdx.x;                   // 0..191
    const int idx   = flat >> 3;                    // 0..23
    const int stile = (flat & 7) * 2 + (idx & 1);   // 0..15 (256 rows each)
    const int ntile = idx >> 1;                     // 0..11 (256 cols each of 3072)
    const unsigned short* Ap = ws + OFF_XB  + (size_t)stile * 256 * D_;
    const unsigned short* Bp = ws + OFF_WQT + (size_t)ntile * 256 * D_;

    __shared__ __align__(16) unsigned short lds[65536];   // 128 KB
    const int tid = threadIdx.x, lane = tid & 63, w = tid >> 6;
    const int lr = lane & 15, lg = lane >> 4;
    const int wm = w >> 2, wn = w & 3;               // wave tile: rows wm*128, cols wn*64

    f32x4 acc[8][4];
#pragma unroll
    for (int i = 0; i < 8; ++i)
#pragma unroll
        for (int j = 0; j < 4; ++j) acc[i][j] = (f32x4){0.f, 0.f, 0.f, 0.f};

    // prologue: kt0 full (8) + kt1 minus A(1,1) (7), in steady-state FIFO order
    qkv_stA(Ap, lds, 0, 0, 0, lane, w, lr, lg);
    qkv_stB(Bp, lds, 0, 0, lane, w, lr, lg);
    qkv_stA(Ap, lds, 0, 1, 0, lane, w, lr, lg);
    qkv_stA(Ap, lds, 0, 0, 1, lane, w, lr, lg);
    qkv_stB(Bp, lds, 0, 1, lane, w, lr, lg);
    qkv_stA(Ap, lds, 0, 1, 1, lane, w, lr, lg);
    qkv_stA(Ap, lds, 1, 0, 0, lane, w, lr, lg);
    qkv_stB(Bp, lds, 1, 0, lane, w, lr, lg);
    qkv_stA(Ap, lds, 1, 1, 0, lane, w, lr, lg);
    qkv_stA(Ap, lds, 1, 0, 1, lane, w, lr, lg);
    qkv_stB(Bp, lds, 1, 1, lane, w, lr, lg);

    for (int kt = 0; kt < 14; ++kt)
        qkv_ktile<12, 12, 12, 12, true, true>(kt, Ap, Bp, lds, lane, w, lr, lg, wm, wn, acc);
    qkv_ktile<12, 12, 9, 8, true, false>(14, Ap, Bp, lds, lane, w, lr, lg, wm, wn, acc);
    qkv_ktile<5, 4, 1, 0, false, false>(15, Ap, Bp, lds, lane, w, lr, lg, wm, wn, acc);

    // epilogue: wave writes one head's 64-col slab. c = ntile*4+wn in 0..47
    const int c = ntile * 4 + wn;
    const int mat = c >> 4, h = c & 15;
    const float* bias = ((mat == 0) ? bq : (mat == 1) ? bk : bv) + h * 64;
    const int bb = stile >> 3;                       // batch (256 | 2048, no straddle)
    const int bh = bb * H_ + h;
#pragma unroll
    for (int mf = 0; mf < 8; ++mf) {
        const int sl = ((stile * 256 + wm * 128 + mf * 16) & (S_ - 1)) + lg * 4;
#pragma unroll
        for (int nf = 0; nf < 4; ++nf) {
            const int e = nf * 16 + lr;
            const float bia = bias[e];
            if (mat == 0) {        // Q^T [BH][E][S], pre-scaled by 0.125*log2e
                u16x4 pk;
#pragma unroll
                for (int r = 0; r < 4; ++r)
                    pk[r] = f2bf((acc[mf][nf][r] + bia) * 0.1803368801f);
                *(u16x4*)(ws + OFF_Q + ((size_t)(bh * E_ + e)) * S_ + sl) = pk;
            } else if (mat == 2) { // V^T [BH][E][S]
                u16x4 pk;
#pragma unroll
                for (int r = 0; r < 4; ++r) pk[r] = f2bf(acc[mf][nf][r] + bia);
                *(u16x4*)(ws + OFF_VT + ((size_t)(bh * E_ + e)) * S_ + sl) = pk;
            } else {               // K [BH][S][E]
#pragma unroll
                for (int r = 0; r < 4; ++r)
                    ws[OFF_K + ((size_t)bh * S_ + sl + r) * E_ + e] =
                        f2bf(acc[mf][nf][r] + bia);
            }
        }
    }
}

// ---------------- GEMM mainloop: C(128x128) (oproj) ----------------
DEVI void gemm_tile_128x128(const unsigned short* __restrict__ A,
                            const unsigned short* __restrict__ Bw,
                            unsigned short* lds,
                            f32x4 acc[2][8]) {
    const int lane = threadIdx.x & 63;
    const int w    = threadIdx.x >> 6;
    const int lr = lane & 15, lg = lane >> 4;
    const unsigned short* a0 = A  + (size_t)((w * 2 + 0) * 16 + lr) * D_ + lg * 8;
    const unsigned short* a1 = A  + (size_t)((w * 2 + 1) * 16 + lr) * D_ + lg * 8;
    const unsigned short* b0 = Bw + (size_t)((w * 2 + 0) * 16 + lr) * D_ + lg * 8;
    const unsigned short* b1 = Bw + (size_t)((w * 2 + 1) * 16 + lr) * D_ + lg * 8;
    const int oA0 = (w * 2 + 0) * 512, oA1 = (w * 2 + 1) * 512;
    const int oB0 = 4096 + oA0,        oB1 = 4096 + oA1;

    auto stage = [&](int ks, int bufi) {
        unsigned short* base = lds + bufi * 8192;
        gload16(a0 + ks * 32, base + oA0);
        gload16(a1 + ks * 32, base + oA1);
        gload16(b0 + ks * 32, base + oB0);
        gload16(b1 + ks * 32, base + oB1);
    };

    stage(0, 0); stage(1, 1);
    for (int ks = 0; ks < 32; ++ks) {
        if (ks < 31) vm_barrier<4>();
        else         vm_barrier<0>();
        if (ks + 2 < 32) stage(ks + 2, (ks + 2) % 3);
        const unsigned short* base = lds + (ks % 3) * 8192;
        bh8 af0 = *(const bh8*)(base + (w * 2 + 0) * 512 + lane * 8);
        bh8 af1 = *(const bh8*)(base + (w * 2 + 1) * 512 + lane * 8);
#pragma unroll
        for (int nt = 0; nt < 8; ++nt) {
            bh8 bf = *(const bh8*)(base + 4096 + nt * 512 + lane * 8);
            acc[0][nt] = mfma16(af0, bf, acc[0][nt]);
            acc[1][nt] = mfma16(af1, bf, acc[1][nt]);
        }
        __builtin_amdgcn_sched_barrier(0);
    }
}

// ---------------- flash attention (causal), swapped-QK^T, KVBLK=128 ----------------
__global__ __launch_bounds__(256, 2) void k_attn(unsigned short* __restrict__ ws) {
    const int flat = blockIdx.x;          // 0..1023
    const int j    = flat & 31;
    const int qt   = 31 - (flat >> 5);    // heavy tiles first
    const int bh   = (j & 7) * 4 + (j >> 3);
    const int lane = threadIdx.x & 63, w = threadIdx.x >> 6;
    const int lr = lane & 15, lg = lane >> 4;
    const unsigned short* Qp = ws + OFF_Q  + (size_t)bh * E_ * S_;   // Q^T [E][S]
    const unsigned short* Kp = ws + OFF_K  + (size_t)bh * S_ * E_;
    const unsigned short* Vp = ws + OFF_VT + (size_t)bh * E_ * S_;
    __shared__ __align__(16) unsigned short ldsK[2][16 * 512];   // 128x64 K tile, frag order
    __shared__ __align__(16) unsigned short ldsV[2][16 * 512];   // 64x128 V^T tile
    __shared__ __align__(16) unsigned short ldsP[4 * 2048];      // per-wave 16x128 P

    const int qbase = qt * 64 + w * 16;   // this wave's 16 q rows
    bh8 qf[2];
#pragma unroll
    for (int kg = 0; kg < 2; ++kg) {
        bh8 t;
#pragma unroll
        for (int i = 0; i < 8; ++i)
            t[i] = (short)Qp[(size_t)(kg * 32 + lg * 8 + i) * S_ + qbase + lr];
        qf[kg] = t;
    }

    f32x4 o[4];
    float m = -3.0e38f, l = 0.f;    // per-lane online state for q = lr (replicated over lg)
#pragma unroll
    for (int i = 0; i < 4; ++i) o[i] = (f32x4){0.f, 0.f, 0.f, 0.f};

    // per wave: 4 K-frags + 4 V-frags (blk = w*4+u in 0..15; LDS slot = blk*512 both)
    auto stage = [&](int kt, int bufi) {
        const int sk0 = kt * 128;
#pragma unroll
        for (int u = 0; u < 4; ++u) {
            const int blk = w * 4 + u;
            const int ct = blk >> 1, kg = blk & 1;       // K frag (ct, kg)
            gload16(Kp + (size_t)(sk0 + ct * 16 + lr) * E_ + kg * 32 + lg * 8,
                    &ldsK[bufi][blk * 512]);
            const int et = blk >> 2, skg = blk & 3;      // V frag (et, skg)
            gload16(Vp + (size_t)(et * 16 + lr) * S_ + sk0 + skg * 32 + lg * 8,
                    &ldsV[bufi][blk * 512]);
        }
    };

    unsigned short* Pw = ldsP + w * 2048;
    const int nkt = (qt >> 1) + 1;

    stage(0, 0);
    if (nkt > 1) stage(1, 1);

    for (int kt = 0; kt < nkt; ++kt) {
        if (kt + 1 < nkt) vm_barrier<8>();
        else              vm_barrier<0>();
        const int cur = kt & 1;
        const unsigned short* Kc = ldsK[cur];
        const unsigned short* Vc = ldsV[cur];

        // S^T = K Q^T (swapped): sc[ct][r] = score[s_k = kt*128+ct*16+lg*4+r][q = lr]
        f32x4 sc[8];
#pragma unroll
        for (int ct = 0; ct < 8; ++ct) sc[ct] = (f32x4){0.f, 0.f, 0.f, 0.f};
#pragma unroll
        for (int ct = 0; ct < 8; ++ct)
#pragma unroll
            for (int kg = 0; kg < 2; ++kg) {
                bh8 kf = *(const bh8*)(Kc + (ct * 2 + kg) * 512 + lane * 8);
                sc[ct] = mfma16(kf, qf[kg], sc[ct]);
            }
        // causal mask: last tile only. off = qt*64 - kt*128 (0 for even qt, 64 for odd)
        if (kt == nkt - 1) {
            const int off = qt * 64 - kt * 128 + w * 16 + lr;
#pragma unroll
            for (int ct = 0; ct < 8; ++ct) {
                const int skl = ct * 16 + lg * 4;
#pragma unroll
                for (int r = 0; r < 4; ++r)
                    if (skl + r > off) sc[ct][r] = -3.0e38f;
            }
        }
        // column (q) max: 31 in-lane fmax + 2 shfl
        float mx = fmaxf(fmaxf(sc[0][0], sc[0][1]), fmaxf(sc[0][2], sc[0][3]));
#pragma unroll
        for (int ct = 1; ct < 8; ++ct)
            mx = fmaxf(mx, fmaxf(fmaxf(sc[ct][0], sc[ct][1]),
                                 fmaxf(sc[ct][2], sc[ct][3])));
        mx = fmaxf(mx, __shfl_xor(mx, 16, 64));
        mx = fmaxf(mx, __shfl_xor(mx, 32, 64));
        // defer-max (T13): rescale only when max grew by > 8 (log2 domain)
        const bool need = mx > m + 8.0f;
        if (__any(need)) {
            const float mn = need ? mx : m;
            const float sf = __builtin_amdgcn_exp2f(m - mn);   // 1.0 when !need
            m = mn;
            l *= sf;
#pragma unroll
            for (int r = 0; r < 4; ++r) {
                const float sfq = __shfl(sf, (lane & 48) + lg * 4 + r, 64);
#pragma unroll
                for (int et = 0; et < 4; ++et) o[et][r] *= sfq;
            }
        }
        // P = exp2(S - m), partial sum in-lane
        float rs = 0.f;
#pragma unroll
        for (int ct = 0; ct < 8; ++ct)
#pragma unroll
            for (int r = 0; r < 4; ++r) {
                float p = __builtin_amdgcn_exp2f(sc[ct][r] - m);
                sc[ct][r] = p;
                rs += p;
            }
        rs += __shfl_xor(rs, 16, 64);
        rs += __shfl_xor(rs, 32, 64);
        l += rs;
        // pack P (cvt_pk) and write A-frag order: 8 x ds_write_b64
#pragma unroll
        for (int ct = 0; ct < 8; ++ct) {
            u32x2 pk = { cvt_pk_bf16(sc[ct][0], sc[ct][1]),
                         cvt_pk_bf16(sc[ct][2], sc[ct][3]) };
            const int addr = (ct >> 1) * 512 +
                             ((((ct & 1) * 2) + (lg >> 1)) * 16 + lr) * 8 + (lg & 1) * 4;
            *(u32x2*)(Pw + addr) = pk;
        }
        // O += P V  (wave-private P; lgkm-ordered, no barrier)
#pragma unroll
        for (int skg = 0; skg < 4; ++skg) {
            bh8 pf = *(const bh8*)(Pw + skg * 512 + lane * 8);
#pragma unroll
            for (int et = 0; et < 4; ++et) {
                bh8 vf = *(const bh8*)(Vc + (et * 4 + skg) * 512 + lane * 8);
                o[et] = mfma16(pf, vf, o[et]);
            }
        }
        post_barrier();
        if (kt + 2 < nkt) stage(kt + 2, cur);
    }
    // epilogue: O/l -> concat layout [B,S,H*64]; l lives at lane with lr = q
    const int b = bh >> 4, hh = bh & 15;
#pragma unroll
    for (int r = 0; r < 4; ++r) {
        const float lq = __shfl(l, (lane & 48) + lg * 4 + r, 64);
        const float inv = 1.0f / lq;
        const int s = qbase + lg * 4 + r;
#pragma unroll
        for (int et = 0; et < 4; ++et)
            ws[OFF_O + ((size_t)(b * S_ + s)) * D_ + hh * E_ + et * 16 + lr] =
                f2bf(o[et][r] * inv);
    }
}

// ---------------- output projection: C[4096,1024] = O * WoT^T ----------------
__global__ __launch_bounds__(256, 3) void k_oproj(const unsigned short* __restrict__ ws,
                                                  const float* __restrict__ bo,
                                                  float* __restrict__ out) {
    const int flat  = blockIdx.x;          // 0..255
    const int idx   = flat >> 3;           // 0..31
    const int stile = (flat & 7) * 4 + (idx & 3);   // 0..31
    const int ntile = idx >> 2;            // 0..7 (128 cols each)
    const unsigned short* A  = ws + OFF_O   + (size_t)stile * 128 * D_;
    const unsigned short* Bw = ws + OFF_WOT + (size_t)ntile * 128 * D_;
    __shared__ __align__(16) unsigned short lds[3 * 8192];
    f32x4 acc[2][8];
#pragma unroll
    for (int i = 0; i < 2; ++i)
#pragma unroll
        for (int j = 0; j < 8; ++j) acc[i][j] = (f32x4){0.f, 0.f, 0.f, 0.f};

    gemm_tile_128x128(A, Bw, lds, acc);

    const int lane = threadIdx.x & 63, w = threadIdx.x >> 6;
    const int lr = lane & 15, lg = lane >> 4;
    const int r0 = stile * 128 + w * 32;
#pragma unroll
    for (int mt = 0; mt < 2; ++mt)
#pragma unroll
        for (int nt = 0; nt < 8; ++nt) {
            const int e = ntile * 128 + nt * 16 + lr;
            const float bia = bo[e];
#pragma unroll
            for (int r = 0; r < 4; ++r)
                out[(size_t)(r0 + mt * 16 + lg * 4 + r) * D_ + e] = acc[mt][nt][r] + bia;
        }
}

extern "C" void kernel_launch(void* const* d_in, const int* in_sizes, int n_in,
                              void* d_out, int out_size, void* d_ws, size_t ws_size,
                              hipStream_t stream) {
    const float* x  = (const float*)d_in[0];
    const float* Wq = (const float*)d_in[1];
    const float* bq = (const float*)d_in[2];
    const float* Wk = (const float*)d_in[3];
    const float* bk = (const float*)d_in[4];
    const float* Wv = (const float*)d_in[5];
    const float* bv = (const float*)d_in[6];
    const float* Wo = (const float*)d_in[7];
    const float* bo = (const float*)d_in[8];
    float* out = (float*)d_out;
    unsigned short* ws = (unsigned short*)d_ws;

    k_prep<<<dim3(5120), 256, 0, stream>>>(x, Wq, Wk, Wv, Wo, ws);
    k_qkv<<<dim3(192), 512, 0, stream>>>(ws, bq, bk, bv);
    k_attn<<<dim3(1024), 256, 0, stream>>>(ws);
    k_oproj<<<dim3(256), 256, 0, stream>>>(ws, bo, out);
}

// Round 18
// 114.611 us; speedup vs baseline: 1.0843x; 1.0193x over previous
//
#include <hip/hip_runtime.h>
#include <stdint.h>

typedef __attribute__((ext_vector_type(8))) short bh8;       // 8 x bf16 (4 VGPR)
typedef __attribute__((ext_vector_type(4))) float f32x4;
typedef __attribute__((ext_vector_type(4))) unsigned short u16x4;
typedef __attribute__((ext_vector_type(8))) unsigned short u16x8;
typedef __attribute__((ext_vector_type(2))) unsigned int u32x2;

#define DEVI static __device__ __forceinline__

constexpr int B_ = 2, S_ = 2048, D_ = 1024, H_ = 16, E_ = 64;

// workspace layout (elements of ushort/bf16)
constexpr size_t OFF_XB  = 0;                              // x as bf16 [B*S, D]
constexpr size_t OFF_WQT = OFF_XB  + (size_t)B_*S_*D_;     // WqT [H, E, D]  } contiguous
constexpr size_t OFF_WKT = OFF_WQT + (size_t)H_*E_*D_;     // WkT [H, E, D]  } = one
constexpr size_t OFF_WVT = OFF_WKT + (size_t)H_*E_*D_;     // WvT [H, E, D]  } [3072,1024]
constexpr size_t OFF_WOT = OFF_WVT + (size_t)H_*E_*D_;     // WoT [D, D]
constexpr size_t OFF_Q   = OFF_WOT + (size_t)D_*D_;        // Q^T [B*H, E, S] (pre-scaled by 0.125*log2e)
constexpr size_t OFF_K   = OFF_Q   + (size_t)B_*H_*S_*E_;  // [B*H, S, E]
constexpr size_t OFF_VT  = OFF_K   + (size_t)B_*H_*S_*E_;  // [B*H, E, S]
constexpr size_t OFF_O   = OFF_VT  + (size_t)B_*H_*S_*E_;  // attn out concat [B*S, D]

DEVI unsigned short f2bf(float f) {
    union { float f; unsigned u; } v; v.f = f;
    unsigned u = v.u;
    return (unsigned short)((u + 0x7fffu + ((u >> 16) & 1u)) >> 16);
}

DEVI unsigned cvt_pk_bf16(float lo, float hi) {   // packs {lo,hi} -> 2 bf16 in one u32
    unsigned r;
    asm("v_cvt_pk_bf16_f32 %0, %1, %2" : "=v"(r) : "v"(lo), "v"(hi));
    return r;
}

DEVI void gload16(const void* g, void* l) {
    __builtin_amdgcn_global_load_lds(
        (const __attribute__((address_space(1))) unsigned int*)g,
        (__attribute__((address_space(3))) unsigned int*)l, 16, 0, 0);
}

DEVI f32x4 mfma16(bh8 a, bh8 b, f32x4 c) {
    return __builtin_amdgcn_mfma_f32_16x16x32_bf16(a, b, c, 0, 0, 0);
}

// counted-vmcnt barrier: prefetched loads stay in flight across the barrier.
template<int N> DEVI void vm_barrier() {
    asm volatile("s_waitcnt vmcnt(%0)" :: "i"(N) : "memory");
    __builtin_amdgcn_s_barrier();
    __builtin_amdgcn_sched_barrier(0);
}
DEVI void post_barrier() {
    __builtin_amdgcn_sched_barrier(0);
    __builtin_amdgcn_s_barrier();
    __builtin_amdgcn_sched_barrier(0);
}

// ---------------- prep (fused): x -> bf16  AND  weights -> bf16 transposed ----------------
__global__ __launch_bounds__(256) void k_prep(const float* __restrict__ x,
                                              const float* __restrict__ Wq,
                                              const float* __restrict__ Wk,
                                              const float* __restrict__ Wv,
                                              const float* __restrict__ Wo,
                                              unsigned short* __restrict__ ws) {
    const int bid = blockIdx.x;
    const int t   = threadIdx.x;
    if (bid < 4096) {
        const int i = bid * 256 + t;
        const float4 v = ((const float4*)x)[i];
        u16x4 o = { f2bf(v.x), f2bf(v.y), f2bf(v.z), f2bf(v.w) };
        *(u16x4*)(ws + OFF_XB + (size_t)i * 4) = o;
        return;
    }
    const int xi = (bid - 4096) & 255;   // 0..255
    const int z  = (bid - 4096) >> 8;    // 0..3
    __shared__ __align__(16) unsigned short tile[64][72];

    const float* src; unsigned short* dst;
    int inCols, inBase, outBase;
    if (z < 3) {
        src = (z == 0) ? Wq : (z == 1) ? Wk : Wv;
        dst = ws + ((z == 0) ? OFF_WQT : (z == 1) ? OFF_WKT : OFF_WVT);
        inCols = 64;
        inBase = xi * 64 * 64;
        const int h = xi >> 4, dt = xi & 15;
        outBase = h * 65536 + dt * 64;
    } else {
        src = Wo; dst = ws + OFF_WOT;
        inCols = 1024;
        const int et = xi >> 4, dt = xi & 15;
        inBase  = (dt * 64) * 1024 + et * 64;
        outBase = (et * 64) * 1024 + dt * 64;
    }
#pragma unroll
    for (int v = 0; v < 4; ++v) {
        const int flat = v * 256 + t;
        const int i = flat >> 4, j4 = (flat & 15) * 4;
        const float4 val = *(const float4*)(src + inBase + i * inCols + j4);
        tile[i][j4 + 0] = f2bf(val.x);
        tile[i][j4 + 1] = f2bf(val.y);
        tile[i][j4 + 2] = f2bf(val.z);
        tile[i][j4 + 3] = f2bf(val.w);
    }
    __syncthreads();
    const int j = t >> 2, iseg = (t & 3) * 16;
    u16x8 p0, p1;
#pragma unroll
    for (int u = 0; u < 8; ++u) p0[u] = tile[iseg + u][j];
#pragma unroll
    for (int u = 0; u < 8; ++u) p1[u] = tile[iseg + 8 + u][j];
    *(u16x8*)(dst + outBase + (size_t)j * 1024 + iseg)     = p0;
    *(u16x8*)(dst + outBase + (size_t)j * 1024 + iseg + 8) = p1;
}

// ================= qkv 256x192 8-phase machinery =================
// LDS (ushort elems): A dbuf [0, 32768) (16 mfrag x 2 ks x 512 per buf);
// B dbuf [32768, 57344) (12 nfrag x 2 ks x 512 per buf = 12288); scratch [57344, 57856).
DEVI void qkv_stA(const unsigned short* Ap, unsigned short* lds, int kt, int mh, int ks,
                  int lane, int w, int lr, int lg) {
    const int b = kt & 1;
    const int mfrag = (w >> 2) * 8 + mh * 4 + (w & 3);
    gload16(Ap + (size_t)(mfrag * 16 + lr) * D_ + kt * 64 + ks * 32 + lg * 8,
            lds + b * 16384 + (mfrag * 2 + ks) * 512 + lane * 8);
}
// B: 12 nfrags/ks. Waves 0-3 load 2 nfrags; waves 4-7 load 1 + 1 dummy (scratch)
// so every wave issues exactly 2 loads -> the per-wave vmcnt FIFO ledger is uniform.
DEVI void qkv_stB(const unsigned short* Bp, unsigned short* lds, int kt, int ks,
                  int lane, int w, int lr, int lg) {
    const int b = kt & 1;
    if (w < 4) {
#pragma unroll
        for (int u = 0; u < 2; ++u) {
            const int nfrag = w * 2 + u;
            gload16(Bp + (size_t)(nfrag * 16 + lr) * D_ + kt * 64 + ks * 32 + lg * 8,
                    lds + 32768 + b * 12288 + (nfrag * 2 + ks) * 512 + lane * 8);
        }
    } else {
        const int nfrag = 4 + w;   // 8..11
        gload16(Bp + (size_t)(nfrag * 16 + lr) * D_ + kt * 64 + ks * 32 + lg * 8,
                lds + 32768 + b * 12288 + (nfrag * 2 + ks) * 512 + lane * 8);
        gload16(Bp + (size_t)lr * D_ + lg * 8, lds + 57344 + lane * 8);   // dummy
    }
}
DEVI bh8 qkv_ldA(const unsigned short* lds, int b, int mfrag, int ks, int lane) {
    return *(const bh8*)(lds + b * 16384 + (mfrag * 2 + ks) * 512 + lane * 8);
}
DEVI bh8 qkv_ldB(const unsigned short* lds, int b, int nfrag, int ks, int lane) {
    return *(const bh8*)(lds + 32768 + b * 12288 + (nfrag * 2 + ks) * 512 + lane * 8);
}

template<int V0, int V1, int V2, int V3, bool S0, bool S123>
DEVI void qkv_ktile(int kt, const unsigned short* Ap, const unsigned short* Bp,
                    unsigned short* lds, int lane, int w, int lr, int lg,
                    int wm, int wn, f32x4 (&acc)[8][3]) {
    const int b = kt & 1;
    bh8 af[4], bf[3];
    // ---- phase 0: quad(mh=0, ks=0); stage A(1,1) of kt+1 ----
    vm_barrier<V0>();
#pragma unroll
    for (int n = 0; n < 3; ++n) bf[n] = qkv_ldB(lds, b, wn * 3 + n, 0, lane);
#pragma unroll
    for (int q = 0; q < 4; ++q) af[q] = qkv_ldA(lds, b, wm * 8 + q, 0, lane);
    if (S0) qkv_stA(Ap, lds, kt + 1, 1, 1, lane, w, lr, lg);
    __builtin_amdgcn_s_setprio(1);
#pragma unroll
    for (int q = 0; q < 4; ++q)
#pragma unroll
        for (int n = 0; n < 3; ++n) acc[q][n] = mfma16(af[q], bf[n], acc[q][n]);
    __builtin_amdgcn_s_setprio(0);
    __builtin_amdgcn_sched_barrier(0);
    // ---- phase 1: quad(1,0); stage A(0,0)+B(ks0) of kt+2 ----
    vm_barrier<V1>();
#pragma unroll
    for (int q = 0; q < 4; ++q) af[q] = qkv_ldA(lds, b, wm * 8 + 4 + q, 0, lane);
    if (S123) {
        qkv_stA(Ap, lds, kt + 2, 0, 0, lane, w, lr, lg);
        qkv_stB(Bp, lds, kt + 2, 0, lane, w, lr, lg);
    }
    __builtin_amdgcn_s_setprio(1);
#pragma unroll
    for (int q = 0; q < 4; ++q)
#pragma unroll
        for (int n = 0; n < 3; ++n) acc[4 + q][n] = mfma16(af[q], bf[n], acc[4 + q][n]);
    __builtin_amdgcn_s_setprio(0);
    __builtin_amdgcn_sched_barrier(0);
    // ---- phase 2: quad(0,1); stage A(1,0) of kt+2 ----
    vm_barrier<V2>();
#pragma unroll
    for (int n = 0; n < 3; ++n) bf[n] = qkv_ldB(lds, b, wn * 3 + n, 1, lane);
#pragma unroll
    for (int q = 0; q < 4; ++q) af[q] = qkv_ldA(lds, b, wm * 8 + q, 1, lane);
    if (S123) qkv_stA(Ap, lds, kt + 2, 1, 0, lane, w, lr, lg);
    __builtin_amdgcn_s_setprio(1);
#pragma unroll
    for (int q = 0; q < 4; ++q)
#pragma unroll
        for (int n = 0; n < 3; ++n) acc[q][n] = mfma16(af[q], bf[n], acc[q][n]);
    __builtin_amdgcn_s_setprio(0);
    __builtin_amdgcn_sched_barrier(0);
    // ---- phase 3: quad(1,1); stage A(0,1)+B(ks1) of kt+2 ----
    vm_barrier<V3>();
#pragma unroll
    for (int q = 0; q < 4; ++q) af[q] = qkv_ldA(lds, b, wm * 8 + 4 + q, 1, lane);
    if (S123) {
        qkv_stA(Ap, lds, kt + 2, 0, 1, lane, w, lr, lg);
        qkv_stB(Bp, lds, kt + 2, 1, lane, w, lr, lg);
    }
    __builtin_amdgcn_s_setprio(1);
#pragma unroll
    for (int q = 0; q < 4; ++q)
#pragma unroll
        for (int n = 0; n < 3; ++n) acc[4 + q][n] = mfma16(af[q], bf[n], acc[4 + q][n]);
    __builtin_amdgcn_s_setprio(0);
    __builtin_amdgcn_sched_barrier(0);
}

// ---------------- fused QKV projection: 256x192 tiles, 8 waves, 8-phase ----------------
// grid 256 = 1 block per CU (full fill; was 192 blocks / 64 CUs idle).
__global__ __launch_bounds__(512, 1) void k_qkv(unsigned short* __restrict__ ws,
                                                const float* __restrict__ bq,
                                                const float* __restrict__ bk,
                                                const float* __restrict__ bv) {
    const int flat  = blockIdx.x;                   // 0..255
    const int stile = (flat & 7) * 2 + ((flat >> 3) & 1);   // 0..15 (256 rows each)
    const int ntile = flat >> 4;                    // 0..15 (192 cols each of 3072)
    const unsigned short* Ap = ws + OFF_XB  + (size_t)stile * 256 * D_;
    const unsigned short* Bp = ws + OFF_WQT + (size_t)ntile * 192 * D_;

    __shared__ __align__(16) unsigned short lds[57856];   // 113 KB
    const int tid = threadIdx.x, lane = tid & 63, w = tid >> 6;
    const int lr = lane & 15, lg = lane >> 4;
    const int wm = w >> 2, wn = w & 3;               // wave tile: rows wm*128, cols wn*48

    f32x4 acc[8][3];
#pragma unroll
    for (int i = 0; i < 8; ++i)
#pragma unroll
        for (int j = 0; j < 3; ++j) acc[i][j] = (f32x4){0.f, 0.f, 0.f, 0.f};

    // prologue: kt0 full (8 loads) + kt1 minus A(1,1) (7), steady-state FIFO order
    qkv_stA(Ap, lds, 0, 0, 0, lane, w, lr, lg);
    qkv_stB(Bp, lds, 0, 0, lane, w, lr, lg);
    qkv_stA(Ap, lds, 0, 1, 0, lane, w, lr, lg);
    qkv_stA(Ap, lds, 0, 0, 1, lane, w, lr, lg);
    qkv_stB(Bp, lds, 0, 1, lane, w, lr, lg);
    qkv_stA(Ap, lds, 0, 1, 1, lane, w, lr, lg);
    qkv_stA(Ap, lds, 1, 0, 0, lane, w, lr, lg);
    qkv_stB(Bp, lds, 1, 0, lane, w, lr, lg);
    qkv_stA(Ap, lds, 1, 1, 0, lane, w, lr, lg);
    qkv_stA(Ap, lds, 1, 0, 1, lane, w, lr, lg);
    qkv_stB(Bp, lds, 1, 1, lane, w, lr, lg);

    for (int kt = 0; kt < 14; ++kt)
        qkv_ktile<12, 12, 12, 12, true, true>(kt, Ap, Bp, lds, lane, w, lr, lg, wm, wn, acc);
    qkv_ktile<12, 12, 9, 8, true, false>(14, Ap, Bp, lds, lane, w, lr, lg, wm, wn, acc);
    qkv_ktile<5, 4, 1, 0, false, false>(15, Ap, Bp, lds, lane, w, lr, lg, wm, wn, acc);

    // epilogue: per 16-col group decode (16 | 64 -> never straddles a head)
    const int bb = stile >> 3;                       // batch (256 | 2048, no straddle)
#pragma unroll
    for (int mf = 0; mf < 8; ++mf) {
        const int sl = ((stile * 256 + wm * 128 + mf * 16) & (S_ - 1)) + lg * 4;
#pragma unroll
        for (int nf = 0; nf < 3; ++nf) {
            const int gcol = ntile * 192 + wn * 48 + nf * 16;
            const int mat  = gcol >> 10;
            const int h    = (gcol >> 6) & 15;
            const int e    = (gcol & 63) + lr;
            const int bh   = bb * H_ + h;
            const float bia = ((mat == 0) ? bq : (mat == 1) ? bk : bv)[h * 64 + e];
            if (mat == 0) {        // Q^T [BH][E][S], pre-scaled by 0.125*log2e
                u16x4 pk;
#pragma unroll
                for (int r = 0; r < 4; ++r)
                    pk[r] = f2bf((acc[mf][nf][r] + bia) * 0.1803368801f);
                *(u16x4*)(ws + OFF_Q + ((size_t)(bh * E_ + e)) * S_ + sl) = pk;
            } else if (mat == 2) { // V^T [BH][E][S]
                u16x4 pk;
#pragma unroll
                for (int r = 0; r < 4; ++r) pk[r] = f2bf(acc[mf][nf][r] + bia);
                *(u16x4*)(ws + OFF_VT + ((size_t)(bh * E_ + e)) * S_ + sl) = pk;
            } else {               // K [BH][S][E]
#pragma unroll
                for (int r = 0; r < 4; ++r)
                    ws[OFF_K + ((size_t)bh * S_ + sl + r) * E_ + e] =
                        f2bf(acc[mf][nf][r] + bia);
            }
        }
    }
}

// ---------------- GEMM mainloop: C(128x128) (oproj) ----------------
DEVI void gemm_tile_128x128(const unsigned short* __restrict__ A,
                            const unsigned short* __restrict__ Bw,
                            unsigned short* lds,
                            f32x4 acc[2][8]) {
    const int lane = threadIdx.x & 63;
    const int w    = threadIdx.x >> 6;
    const int lr = lane & 15, lg = lane >> 4;
    const unsigned short* a0 = A  + (size_t)((w * 2 + 0) * 16 + lr) * D_ + lg * 8;
    const unsigned short* a1 = A  + (size_t)((w * 2 + 1) * 16 + lr) * D_ + lg * 8;
    const unsigned short* b0 = Bw + (size_t)((w * 2 + 0) * 16 + lr) * D_ + lg * 8;
    const unsigned short* b1 = Bw + (size_t)((w * 2 + 1) * 16 + lr) * D_ + lg * 8;
    const int oA0 = (w * 2 + 0) * 512, oA1 = (w * 2 + 1) * 512;
    const int oB0 = 4096 + oA0,        oB1 = 4096 + oA1;

    auto stage = [&](int ks, int bufi) {
        unsigned short* base = lds + bufi * 8192;
        gload16(a0 + ks * 32, base + oA0);
        gload16(a1 + ks * 32, base + oA1);
        gload16(b0 + ks * 32, base + oB0);
        gload16(b1 + ks * 32, base + oB1);
    };

    stage(0, 0); stage(1, 1);
    for (int ks = 0; ks < 32; ++ks) {
        if (ks < 31) vm_barrier<4>();
        else         vm_barrier<0>();
        if (ks + 2 < 32) stage(ks + 2, (ks + 2) % 3);
        const unsigned short* base = lds + (ks % 3) * 8192;
        bh8 af0 = *(const bh8*)(base + (w * 2 + 0) * 512 + lane * 8);
        bh8 af1 = *(const bh8*)(base + (w * 2 + 1) * 512 + lane * 8);
#pragma unroll
        for (int nt = 0; nt < 8; ++nt) {
            bh8 bf = *(const bh8*)(base + 4096 + nt * 512 + lane * 8);
            acc[0][nt] = mfma16(af0, bf, acc[0][nt]);
            acc[1][nt] = mfma16(af1, bf, acc[1][nt]);
        }
        __builtin_amdgcn_sched_barrier(0);
    }
}

// ---------------- flash attention (causal), swapped-QK^T, KVBLK=128 ----------------
__global__ __launch_bounds__(256, 2) void k_attn(unsigned short* __restrict__ ws) {
    const int flat = blockIdx.x;          // 0..1023
    const int j    = flat & 31;
    const int qt   = 31 - (flat >> 5);    // heavy tiles first
    const int bh   = (j & 7) * 4 + (j >> 3);
    const int lane = threadIdx.x & 63, w = threadIdx.x >> 6;
    const int lr = lane & 15, lg = lane >> 4;
    const unsigned short* Qp = ws + OFF_Q  + (size_t)bh * E_ * S_;   // Q^T [E][S]
    const unsigned short* Kp = ws + OFF_K  + (size_t)bh * S_ * E_;
    const unsigned short* Vp = ws + OFF_VT + (size_t)bh * E_ * S_;
    __shared__ __align__(16) unsigned short ldsK[2][16 * 512];   // 128x64 K tile, frag order
    __shared__ __align__(16) unsigned short ldsV[2][16 * 512];   // 64x128 V^T tile
    __shared__ __align__(16) unsigned short ldsP[4 * 2048];      // per-wave 16x128 P

    const int qbase = qt * 64 + w * 16;   // this wave's 16 q rows
    bh8 qf[2];
#pragma unroll
    for (int kg = 0; kg < 2; ++kg) {
        bh8 t;
#pragma unroll
        for (int i = 0; i < 8; ++i)
            t[i] = (short)Qp[(size_t)(kg * 32 + lg * 8 + i) * S_ + qbase + lr];
        qf[kg] = t;
    }

    f32x4 o[4];
    float m = -3.0e38f, l = 0.f;    // per-lane online state for q = lr (replicated over lg)
#pragma unroll
    for (int i = 0; i < 4; ++i) o[i] = (f32x4){0.f, 0.f, 0.f, 0.f};

    // per wave: 4 K-frags + 4 V-frags (blk = w*4+u in 0..15; LDS slot = blk*512 both)
    auto stage = [&](int kt, int bufi) {
        const int sk0 = kt * 128;
#pragma unroll
        for (int u = 0; u < 4; ++u) {
            const int blk = w * 4 + u;
            const int ct = blk >> 1, kg = blk & 1;       // K frag (ct, kg)
            gload16(Kp + (size_t)(sk0 + ct * 16 + lr) * E_ + kg * 32 + lg * 8,
                    &ldsK[bufi][blk * 512]);
            const int et = blk >> 2, skg = blk & 3;      // V frag (et, skg)
            gload16(Vp + (size_t)(et * 16 + lr) * S_ + sk0 + skg * 32 + lg * 8,
                    &ldsV[bufi][blk * 512]);
        }
    };

    unsigned short* Pw = ldsP + w * 2048;
    const int nkt = (qt >> 1) + 1;

    stage(0, 0);
    if (nkt > 1) stage(1, 1);

    for (int kt = 0; kt < nkt; ++kt) {
        if (kt + 1 < nkt) vm_barrier<8>();
        else              vm_barrier<0>();
        const int cur = kt & 1;
        const unsigned short* Kc = ldsK[cur];
        const unsigned short* Vc = ldsV[cur];

        // S^T = K Q^T (swapped): sc[ct][r] = score[s_k = kt*128+ct*16+lg*4+r][q = lr]
        f32x4 sc[8];
#pragma unroll
        for (int ct = 0; ct < 8; ++ct) sc[ct] = (f32x4){0.f, 0.f, 0.f, 0.f};
#pragma unroll
        for (int ct = 0; ct < 8; ++ct)
#pragma unroll
            for (int kg = 0; kg < 2; ++kg) {
                bh8 kf = *(const bh8*)(Kc + (ct * 2 + kg) * 512 + lane * 8);
                sc[ct] = mfma16(kf, qf[kg], sc[ct]);
            }
        // causal mask: last tile only. off = qt*64 - kt*128 (0 for even qt, 64 for odd)
        if (kt == nkt - 1) {
            const int off = qt * 64 - kt * 128 + w * 16 + lr;
#pragma unroll
            for (int ct = 0; ct < 8; ++ct) {
                const int skl = ct * 16 + lg * 4;
#pragma unroll
                for (int r = 0; r < 4; ++r)
                    if (skl + r > off) sc[ct][r] = -3.0e38f;
            }
        }
        // column (q) max: 31 in-lane fmax + 2 shfl
        float mx = fmaxf(fmaxf(sc[0][0], sc[0][1]), fmaxf(sc[0][2], sc[0][3]));
#pragma unroll
        for (int ct = 1; ct < 8; ++ct)
            mx = fmaxf(mx, fmaxf(fmaxf(sc[ct][0], sc[ct][1]),
                                 fmaxf(sc[ct][2], sc[ct][3])));
        mx = fmaxf(mx, __shfl_xor(mx, 16, 64));
        mx = fmaxf(mx, __shfl_xor(mx, 32, 64));
        // defer-max (T13): rescale only when max grew by > 8 (log2 domain)
        const bool need = mx > m + 8.0f;
        if (__any(need)) {
            const float mn = need ? mx : m;
            const float sf = __builtin_amdgcn_exp2f(m - mn);   // 1.0 when !need
            m = mn;
            l *= sf;
#pragma unroll
            for (int r = 0; r < 4; ++r) {
                const float sfq = __shfl(sf, (lane & 48) + lg * 4 + r, 64);
#pragma unroll
                for (int et = 0; et < 4; ++et) o[et][r] *= sfq;
            }
        }
        // P = exp2(S - m), partial sum in-lane
        float rs = 0.f;
#pragma unroll
        for (int ct = 0; ct < 8; ++ct)
#pragma unroll
            for (int r = 0; r < 4; ++r) {
                float p = __builtin_amdgcn_exp2f(sc[ct][r] - m);
                sc[ct][r] = p;
                rs += p;
            }
        rs += __shfl_xor(rs, 16, 64);
        rs += __shfl_xor(rs, 32, 64);
        l += rs;
        // pack P (cvt_pk) and write A-frag order: 8 x ds_write_b64
#pragma unroll
        for (int ct = 0; ct < 8; ++ct) {
            u32x2 pk = { cvt_pk_bf16(sc[ct][0], sc[ct][1]),
                         cvt_pk_bf16(sc[ct][2], sc[ct][3]) };
            const int addr = (ct >> 1) * 512 +
                             ((((ct & 1) * 2) + (lg >> 1)) * 16 + lr) * 8 + (lg & 1) * 4;
            *(u32x2*)(Pw + addr) = pk;
        }
        // O += P V  (wave-private P; lgkm-ordered, no barrier)
#pragma unroll
        for (int skg = 0; skg < 4; ++skg) {
            bh8 pf = *(const bh8*)(Pw + skg * 512 + lane * 8);
#pragma unroll
            for (int et = 0; et < 4; ++et) {
                bh8 vf = *(const bh8*)(Vc + (et * 4 + skg) * 512 + lane * 8);
                o[et] = mfma16(pf, vf, o[et]);
            }
        }
        post_barrier();
        if (kt + 2 < nkt) stage(kt + 2, cur);
    }
    // epilogue: O/l -> concat layout [B,S,H*64]; l lives at lane with lr = q
    const int b = bh >> 4, hh = bh & 15;
#pragma unroll
    for (int r = 0; r < 4; ++r) {
        const float lq = __shfl(l, (lane & 48) + lg * 4 + r, 64);
        const float inv = 1.0f / lq;
        const int s = qbase + lg * 4 + r;
#pragma unroll
        for (int et = 0; et < 4; ++et)
            ws[OFF_O + ((size_t)(b * S_ + s)) * D_ + hh * E_ + et * 16 + lr] =
                f2bf(o[et][r] * inv);
    }
}

// ---------------- output projection: C[4096,1024] = O * WoT^T ----------------
__global__ __launch_bounds__(256, 3) void k_oproj(const unsigned short* __restrict__ ws,
                                                  const float* __restrict__ bo,
                                                  float* __restrict__ out) {
    const int flat  = blockIdx.x;          // 0..255
    const int idx   = flat >> 3;           // 0..31
    const int stile = (flat & 7) * 4 + (idx & 3);   // 0..31
    const int ntile = idx >> 2;            // 0..7 (128 cols each)
    const unsigned short* A  = ws + OFF_O   + (size_t)stile * 128 * D_;
    const unsigned short* Bw = ws + OFF_WOT + (size_t)ntile * 128 * D_;
    __shared__ __align__(16) unsigned short lds[3 * 8192];
    f32x4 acc[2][8];
#pragma unroll
    for (int i = 0; i < 2; ++i)
#pragma unroll
        for (int j = 0; j < 8; ++j) acc[i][j] = (f32x4){0.f, 0.f, 0.f, 0.f};

    gemm_tile_128x128(A, Bw, lds, acc);

    const int lane = threadIdx.x & 63, w = threadIdx.x >> 6;
    const int lr = lane & 15, lg = lane >> 4;
    const int r0 = stile * 128 + w * 32;
#pragma unroll
    for (int mt = 0; mt < 2; ++mt)
#pragma unroll
        for (int nt = 0; nt < 8; ++nt) {
            const int e = ntile * 128 + nt * 16 + lr;
            const float bia = bo[e];
#pragma unroll
            for (int r = 0; r < 4; ++r)
                out[(size_t)(r0 + mt * 16 + lg * 4 + r) * D_ + e] = acc[mt][nt][r] + bia;
        }
}

extern "C" void kernel_launch(void* const* d_in, const int* in_sizes, int n_in,
                              void* d_out, int out_size, void* d_ws, size_t ws_size,
                              hipStream_t stream) {
    const float* x  = (const float*)d_in[0];
    const float* Wq = (const float*)d_in[1];
    const float* bq = (const float*)d_in[2];
    const float* Wk = (const float*)d_in[3];
    const float* bk = (const float*)d_in[4];
    const float* Wv = (const float*)d_in[5];
    const float* bv = (const float*)d_in[6];
    const float* Wo = (const float*)d_in[7];
    const float* bo = (const float*)d_in[8];
    float* out = (float*)d_out;
    unsigned short* ws = (unsigned short*)d_ws;

    k_prep<<<dim3(5120), 256, 0, stream>>>(x, Wq, Wk, Wv, Wo, ws);
    k_qkv<<<dim3(256), 512, 0, stream>>>(ws, bq, bk, bv);
    k_attn<<<dim3(1024), 256, 0, stream>>>(ws);
    k_oproj<<<dim3(256), 256, 0, stream>>>(ws, bo, out);
}

// Round 19
// 114.468 us; speedup vs baseline: 1.0856x; 1.0012x over previous
//
#include <hip/hip_runtime.h>
#include <stdint.h>

typedef __attribute__((ext_vector_type(8))) short bh8;       // 8 x bf16 (4 VGPR)
typedef __attribute__((ext_vector_type(4))) float f32x4;
typedef __attribute__((ext_vector_type(4))) unsigned short u16x4;
typedef __attribute__((ext_vector_type(8))) unsigned short u16x8;
typedef __attribute__((ext_vector_type(2))) unsigned int u32x2;

#define DEVI static __device__ __forceinline__

constexpr int B_ = 2, S_ = 2048, D_ = 1024, H_ = 16, E_ = 64;

// workspace layout (elements of ushort/bf16)
constexpr size_t OFF_XB  = 0;                              // x as bf16 [B*S, D]
constexpr size_t OFF_WQT = OFF_XB  + (size_t)B_*S_*D_;     // WqT [H, E, D]  } contiguous
constexpr size_t OFF_WKT = OFF_WQT + (size_t)H_*E_*D_;     // WkT [H, E, D]  } = one
constexpr size_t OFF_WVT = OFF_WKT + (size_t)H_*E_*D_;     // WvT [H, E, D]  } [3072,1024]
constexpr size_t OFF_WOT = OFF_WVT + (size_t)H_*E_*D_;     // WoT [D, D]
constexpr size_t OFF_Q   = OFF_WOT + (size_t)D_*D_;        // Q^T [B*H, E, S] (pre-scaled by 0.125*log2e)
constexpr size_t OFF_K   = OFF_Q   + (size_t)B_*H_*S_*E_;  // [B*H, S, E]
constexpr size_t OFF_VT  = OFF_K   + (size_t)B_*H_*S_*E_;  // [B*H, E, S]
constexpr size_t OFF_O   = OFF_VT  + (size_t)B_*H_*S_*E_;  // attn out concat [B*S, D]

DEVI unsigned short f2bf(float f) {
    union { float f; unsigned u; } v; v.f = f;
    unsigned u = v.u;
    return (unsigned short)((u + 0x7fffu + ((u >> 16) & 1u)) >> 16);
}

DEVI unsigned cvt_pk_bf16(float lo, float hi) {   // packs {lo,hi} -> 2 bf16 in one u32
    unsigned r;
    asm("v_cvt_pk_bf16_f32 %0, %1, %2" : "=v"(r) : "v"(lo), "v"(hi));
    return r;
}

DEVI void gload16(const void* g, void* l) {
    __builtin_amdgcn_global_load_lds(
        (const __attribute__((address_space(1))) unsigned int*)g,
        (__attribute__((address_space(3))) unsigned int*)l, 16, 0, 0);
}

DEVI f32x4 mfma16(bh8 a, bh8 b, f32x4 c) {
    return __builtin_amdgcn_mfma_f32_16x16x32_bf16(a, b, c, 0, 0, 0);
}

// counted-vmcnt barrier: prefetched loads stay in flight across the barrier.
template<int N> DEVI void vm_barrier() {
    asm volatile("s_waitcnt vmcnt(%0)" :: "i"(N) : "memory");
    __builtin_amdgcn_s_barrier();
    __builtin_amdgcn_sched_barrier(0);
}
DEVI void post_barrier() {
    __builtin_amdgcn_sched_barrier(0);
    __builtin_amdgcn_s_barrier();
    __builtin_amdgcn_sched_barrier(0);
}

// ---------------- prep (fused): x -> bf16  AND  weights -> bf16 transposed ----------------
__global__ __launch_bounds__(256) void k_prep(const float* __restrict__ x,
                                              const float* __restrict__ Wq,
                                              const float* __restrict__ Wk,
                                              const float* __restrict__ Wv,
                                              const float* __restrict__ Wo,
                                              unsigned short* __restrict__ ws) {
    const int bid = blockIdx.x;
    const int t   = threadIdx.x;
    if (bid < 4096) {
        const int i = bid * 256 + t;
        const float4 v = ((const float4*)x)[i];
        u16x4 o = { f2bf(v.x), f2bf(v.y), f2bf(v.z), f2bf(v.w) };
        *(u16x4*)(ws + OFF_XB + (size_t)i * 4) = o;
        return;
    }
    const int xi = (bid - 4096) & 255;   // 0..255
    const int z  = (bid - 4096) >> 8;    // 0..3
    __shared__ __align__(16) unsigned short tile[64][72];

    const float* src; unsigned short* dst;
    int inCols, inBase, outBase;
    if (z < 3) {
        src = (z == 0) ? Wq : (z == 1) ? Wk : Wv;
        dst = ws + ((z == 0) ? OFF_WQT : (z == 1) ? OFF_WKT : OFF_WVT);
        inCols = 64;
        inBase = xi * 64 * 64;
        const int h = xi >> 4, dt = xi & 15;
        outBase = h * 65536 + dt * 64;
    } else {
        src = Wo; dst = ws + OFF_WOT;
        inCols = 1024;
        const int et = xi >> 4, dt = xi & 15;
        inBase  = (dt * 64) * 1024 + et * 64;
        outBase = (et * 64) * 1024 + dt * 64;
    }
#pragma unroll
    for (int v = 0; v < 4; ++v) {
        const int flat = v * 256 + t;
        const int i = flat >> 4, j4 = (flat & 15) * 4;
        const float4 val = *(const float4*)(src + inBase + i * inCols + j4);
        tile[i][j4 + 0] = f2bf(val.x);
        tile[i][j4 + 1] = f2bf(val.y);
        tile[i][j4 + 2] = f2bf(val.z);
        tile[i][j4 + 3] = f2bf(val.w);
    }
    __syncthreads();
    const int j = t >> 2, iseg = (t & 3) * 16;
    u16x8 p0, p1;
#pragma unroll
    for (int u = 0; u < 8; ++u) p0[u] = tile[iseg + u][j];
#pragma unroll
    for (int u = 0; u < 8; ++u) p1[u] = tile[iseg + 8 + u][j];
    *(u16x8*)(dst + outBase + (size_t)j * 1024 + iseg)     = p0;
    *(u16x8*)(dst + outBase + (size_t)j * 1024 + iseg + 8) = p1;
}

// ================= qkv 256x192 8-phase machinery =================
// LDS (ushort elems): A dbuf [0, 32768); B dbuf [32768, 57344); scratch [57344, 57856).
DEVI void qkv_stA(const unsigned short* Ap, unsigned short* lds, int kt, int mh, int ks,
                  int lane, int w, int lr, int lg) {
    const int b = kt & 1;
    const int mfrag = (w >> 2) * 8 + mh * 4 + (w & 3);
    gload16(Ap + (size_t)(mfrag * 16 + lr) * D_ + kt * 64 + ks * 32 + lg * 8,
            lds + b * 16384 + (mfrag * 2 + ks) * 512 + lane * 8);
}
// B: 12 nfrags/ks. Waves 0-3 load 2 nfrags; waves 4-7 load 1 + 1 dummy (scratch)
// so every wave issues exactly 2 loads -> per-wave vmcnt FIFO ledger uniform.
DEVI void qkv_stB(const unsigned short* Bp, unsigned short* lds, int kt, int ks,
                  int lane, int w, int lr, int lg) {
    const int b = kt & 1;
    if (w < 4) {
#pragma unroll
        for (int u = 0; u < 2; ++u) {
            const int nfrag = w * 2 + u;
            gload16(Bp + (size_t)(nfrag * 16 + lr) * D_ + kt * 64 + ks * 32 + lg * 8,
                    lds + 32768 + b * 12288 + (nfrag * 2 + ks) * 512 + lane * 8);
        }
    } else {
        const int nfrag = 4 + w;   // 8..11
        gload16(Bp + (size_t)(nfrag * 16 + lr) * D_ + kt * 64 + ks * 32 + lg * 8,
                lds + 32768 + b * 12288 + (nfrag * 2 + ks) * 512 + lane * 8);
        gload16(Bp + (size_t)lr * D_ + lg * 8, lds + 57344 + lane * 8);   // dummy
    }
}
DEVI bh8 qkv_ldA(const unsigned short* lds, int b, int mfrag, int ks, int lane) {
    return *(const bh8*)(lds + b * 16384 + (mfrag * 2 + ks) * 512 + lane * 8);
}
DEVI bh8 qkv_ldB(const unsigned short* lds, int b, int nfrag, int ks, int lane) {
    return *(const bh8*)(lds + 32768 + b * 12288 + (nfrag * 2 + ks) * 512 + lane * 8);
}

// Register-pipelined 8-phase K-tile: each phase's MFMA consumes fragments whose
// ds_reads were ISSUED a full phase earlier (LDS latency hidden under the phase).
// Deeper vmcnt ledger (regions resident one phase early): steady <11,9,11,12>;
// P0 needs A00,B0,A10; P1 needs A01,B1; P2 needs A11; P3 none.
// WAR: every prefetched region's reads complete (lgkm before consuming MFMA) one
// barrier before any wave stages into it (af1 overwritten at P2, af2 at P3,
// bf1 at P3, af3 at next tile's P0).
template<int V0, int V1, int V2, int V3, bool S0, bool S123>
DEVI void qkv_ktile(int kt, const unsigned short* Ap, const unsigned short* Bp,
                    unsigned short* lds, int lane, int w, int lr, int lg,
                    int wm, int wn, f32x4 (&acc)[8][3]) {
    const int b = kt & 1;
    bh8 af0[4], af1[4], af2[4], af3[4], bf0[3], bf1[3];
    // ---- phase 0: MFMA quad(mh0,ks0); issue reads for quad(mh1,ks0) ----
    vm_barrier<V0>();
#pragma unroll
    for (int n = 0; n < 3; ++n) bf0[n] = qkv_ldB(lds, b, wn * 3 + n, 0, lane);
#pragma unroll
    for (int q = 0; q < 4; ++q) af0[q] = qkv_ldA(lds, b, wm * 8 + q, 0, lane);
#pragma unroll
    for (int q = 0; q < 4; ++q) af1[q] = qkv_ldA(lds, b, wm * 8 + 4 + q, 0, lane);
    if (S0) qkv_stA(Ap, lds, kt + 1, 1, 1, lane, w, lr, lg);
    __builtin_amdgcn_s_setprio(1);
#pragma unroll
    for (int q = 0; q < 4; ++q)
#pragma unroll
        for (int n = 0; n < 3; ++n) acc[q][n] = mfma16(af0[q], bf0[n], acc[q][n]);
    __builtin_amdgcn_s_setprio(0);
    __builtin_amdgcn_sched_barrier(0);
    // ---- phase 1: MFMA quad(mh1,ks0) [regs from P0]; issue reads for (mh0,ks1)+B(ks1) ----
    vm_barrier<V1>();
#pragma unroll
    for (int n = 0; n < 3; ++n) bf1[n] = qkv_ldB(lds, b, wn * 3 + n, 1, lane);
#pragma unroll
    for (int q = 0; q < 4; ++q) af2[q] = qkv_ldA(lds, b, wm * 8 + q, 1, lane);
    if (S123) {
        qkv_stA(Ap, lds, kt + 2, 0, 0, lane, w, lr, lg);
        qkv_stB(Bp, lds, kt + 2, 0, lane, w, lr, lg);
    }
    __builtin_amdgcn_s_setprio(1);
#pragma unroll
    for (int q = 0; q < 4; ++q)
#pragma unroll
        for (int n = 0; n < 3; ++n) acc[4 + q][n] = mfma16(af1[q], bf0[n], acc[4 + q][n]);
    __builtin_amdgcn_s_setprio(0);
    __builtin_amdgcn_sched_barrier(0);
    // ---- phase 2: MFMA quad(mh0,ks1) [regs from P1]; issue reads for (mh1,ks1) ----
    vm_barrier<V2>();
#pragma unroll
    for (int q = 0; q < 4; ++q) af3[q] = qkv_ldA(lds, b, wm * 8 + 4 + q, 1, lane);
    if (S123) qkv_stA(Ap, lds, kt + 2, 1, 0, lane, w, lr, lg);
    __builtin_amdgcn_s_setprio(1);
#pragma unroll
    for (int q = 0; q < 4; ++q)
#pragma unroll
        for (int n = 0; n < 3; ++n) acc[q][n] = mfma16(af2[q], bf1[n], acc[q][n]);
    __builtin_amdgcn_s_setprio(0);
    __builtin_amdgcn_sched_barrier(0);
    // ---- phase 3: MFMA quad(mh1,ks1) [regs from P2] ----
    vm_barrier<V3>();
    if (S123) {
        qkv_stA(Ap, lds, kt + 2, 0, 1, lane, w, lr, lg);
        qkv_stB(Bp, lds, kt + 2, 1, lane, w, lr, lg);
    }
    __builtin_amdgcn_s_setprio(1);
#pragma unroll
    for (int q = 0; q < 4; ++q)
#pragma unroll
        for (int n = 0; n < 3; ++n) acc[4 + q][n] = mfma16(af3[q], bf1[n], acc[4 + q][n]);
    __builtin_amdgcn_s_setprio(0);
    __builtin_amdgcn_sched_barrier(0);
}

// ---------------- fused QKV projection: 256x192 tiles, 8 waves, 8-phase ----------------
__global__ __launch_bounds__(512, 1) void k_qkv(unsigned short* __restrict__ ws,
                                                const float* __restrict__ bq,
                                                const float* __restrict__ bk,
                                                const float* __restrict__ bv) {
    const int flat  = blockIdx.x;                   // 0..255
    const int stile = (flat & 7) * 2 + ((flat >> 3) & 1);   // 0..15 (256 rows each)
    const int ntile = flat >> 4;                    // 0..15 (192 cols each of 3072)
    const unsigned short* Ap = ws + OFF_XB  + (size_t)stile * 256 * D_;
    const unsigned short* Bp = ws + OFF_WQT + (size_t)ntile * 192 * D_;

    __shared__ __align__(16) unsigned short lds[57856];   // 113 KB
    const int tid = threadIdx.x, lane = tid & 63, w = tid >> 6;
    const int lr = lane & 15, lg = lane >> 4;
    const int wm = w >> 2, wn = w & 3;               // wave tile: rows wm*128, cols wn*48

    f32x4 acc[8][3];
#pragma unroll
    for (int i = 0; i < 8; ++i)
#pragma unroll
        for (int j = 0; j < 3; ++j) acc[i][j] = (f32x4){0.f, 0.f, 0.f, 0.f};

    // prologue: kt0 full (8 loads) + kt1 minus A(1,1) (7), steady-state FIFO order
    qkv_stA(Ap, lds, 0, 0, 0, lane, w, lr, lg);
    qkv_stB(Bp, lds, 0, 0, lane, w, lr, lg);
    qkv_stA(Ap, lds, 0, 1, 0, lane, w, lr, lg);
    qkv_stA(Ap, lds, 0, 0, 1, lane, w, lr, lg);
    qkv_stB(Bp, lds, 0, 1, lane, w, lr, lg);
    qkv_stA(Ap, lds, 0, 1, 1, lane, w, lr, lg);
    qkv_stA(Ap, lds, 1, 0, 0, lane, w, lr, lg);
    qkv_stB(Bp, lds, 1, 0, lane, w, lr, lg);
    qkv_stA(Ap, lds, 1, 1, 0, lane, w, lr, lg);
    qkv_stA(Ap, lds, 1, 0, 1, lane, w, lr, lg);
    qkv_stB(Bp, lds, 1, 1, lane, w, lr, lg);

    for (int kt = 0; kt < 14; ++kt)
        qkv_ktile<11, 9, 11, 12, true, true>(kt, Ap, Bp, lds, lane, w, lr, lg, wm, wn, acc);
    qkv_ktile<11, 9, 8, 8, true, false>(14, Ap, Bp, lds, lane, w, lr, lg, wm, wn, acc);
    qkv_ktile<4, 1, 0, 0, false, false>(15, Ap, Bp, lds, lane, w, lr, lg, wm, wn, acc);

    // epilogue: per 16-col group decode (16 | 64 -> never straddles a head)
    const int bb = stile >> 3;                       // batch (256 | 2048, no straddle)
#pragma unroll
    for (int mf = 0; mf < 8; ++mf) {
        const int sl = ((stile * 256 + wm * 128 + mf * 16) & (S_ - 1)) + lg * 4;
#pragma unroll
        for (int nf = 0; nf < 3; ++nf) {
            const int gcol = ntile * 192 + wn * 48 + nf * 16;
            const int mat  = gcol >> 10;
            const int h    = (gcol >> 6) & 15;
            const int e    = (gcol & 63) + lr;
            const int bh   = bb * H_ + h;
            const float bia = ((mat == 0) ? bq : (mat == 1) ? bk : bv)[h * 64 + e];
            if (mat == 0) {        // Q^T [BH][E][S], pre-scaled by 0.125*log2e
                u16x4 pk;
#pragma unroll
                for (int r = 0; r < 4; ++r)
                    pk[r] = f2bf((acc[mf][nf][r] + bia) * 0.1803368801f);
                *(u16x4*)(ws + OFF_Q + ((size_t)(bh * E_ + e)) * S_ + sl) = pk;
            } else if (mat == 2) { // V^T [BH][E][S]
                u16x4 pk;
#pragma unroll
                for (int r = 0; r < 4; ++r) pk[r] = f2bf(acc[mf][nf][r] + bia);
                *(u16x4*)(ws + OFF_VT + ((size_t)(bh * E_ + e)) * S_ + sl) = pk;
            } else {               // K [BH][S][E]
#pragma unroll
                for (int r = 0; r < 4; ++r)
                    ws[OFF_K + ((size_t)bh * S_ + sl + r) * E_ + e] =
                        f2bf(acc[mf][nf][r] + bia);
            }
        }
    }
}

// ---------------- GEMM mainloop: C(128x128) (oproj) ----------------
DEVI void gemm_tile_128x128(const unsigned short* __restrict__ A,
                            const unsigned short* __restrict__ Bw,
                            unsigned short* lds,
                            f32x4 acc[2][8]) {
    const int lane = threadIdx.x & 63;
    const int w    = threadIdx.x >> 6;
    const int lr = lane & 15, lg = lane >> 4;
    const unsigned short* a0 = A  + (size_t)((w * 2 + 0) * 16 + lr) * D_ + lg * 8;
    const unsigned short* a1 = A  + (size_t)((w * 2 + 1) * 16 + lr) * D_ + lg * 8;
    const unsigned short* b0 = Bw + (size_t)((w * 2 + 0) * 16 + lr) * D_ + lg * 8;
    const unsigned short* b1 = Bw + (size_t)((w * 2 + 1) * 16 + lr) * D_ + lg * 8;
    const int oA0 = (w * 2 + 0) * 512, oA1 = (w * 2 + 1) * 512;
    const int oB0 = 4096 + oA0,        oB1 = 4096 + oA1;

    auto stage = [&](int ks, int bufi) {
        unsigned short* base = lds + bufi * 8192;
        gload16(a0 + ks * 32, base + oA0);
        gload16(a1 + ks * 32, base + oA1);
        gload16(b0 + ks * 32, base + oB0);
        gload16(b1 + ks * 32, base + oB1);
    };

    stage(0, 0); stage(1, 1);
    for (int ks = 0; ks < 32; ++ks) {
        if (ks < 31) vm_barrier<4>();
        else         vm_barrier<0>();
        if (ks + 2 < 32) stage(ks + 2, (ks + 2) % 3);
        const unsigned short* base = lds + (ks % 3) * 8192;
        bh8 af0 = *(const bh8*)(base + (w * 2 + 0) * 512 + lane * 8);
        bh8 af1 = *(const bh8*)(base + (w * 2 + 1) * 512 + lane * 8);
#pragma unroll
        for (int nt = 0; nt < 8; ++nt) {
            bh8 bf = *(const bh8*)(base + 4096 + nt * 512 + lane * 8);
            acc[0][nt] = mfma16(af0, bf, acc[0][nt]);
            acc[1][nt] = mfma16(af1, bf, acc[1][nt]);
        }
        __builtin_amdgcn_sched_barrier(0);
    }
}

// ---------------- flash attention (causal), swapped-QK^T, KVBLK=128 ----------------
__global__ __launch_bounds__(256, 2) void k_attn(unsigned short* __restrict__ ws) {
    const int flat = blockIdx.x;          // 0..1023
    const int j    = flat & 31;
    const int qt   = 31 - (flat >> 5);    // heavy tiles first
    const int bh   = (j & 7) * 4 + (j >> 3);
    const int lane = threadIdx.x & 63, w = threadIdx.x >> 6;
    const int lr = lane & 15, lg = lane >> 4;
    const unsigned short* Qp = ws + OFF_Q  + (size_t)bh * E_ * S_;   // Q^T [E][S]
    const unsigned short* Kp = ws + OFF_K  + (size_t)bh * S_ * E_;
    const unsigned short* Vp = ws + OFF_VT + (size_t)bh * E_ * S_;
    __shared__ __align__(16) unsigned short ldsK[2][16 * 512];   // 128x64 K tile, frag order
    __shared__ __align__(16) unsigned short ldsV[2][16 * 512];   // 64x128 V^T tile
    __shared__ __align__(16) unsigned short ldsP[4 * 2048];      // per-wave 16x128 P

    const int qbase = qt * 64 + w * 16;   // this wave's 16 q rows
    bh8 qf[2];
#pragma unroll
    for (int kg = 0; kg < 2; ++kg) {
        bh8 t;
#pragma unroll
        for (int i = 0; i < 8; ++i)
            t[i] = (short)Qp[(size_t)(kg * 32 + lg * 8 + i) * S_ + qbase + lr];
        qf[kg] = t;
    }

    f32x4 o[4];
    float m = -3.0e38f, l = 0.f;    // per-lane online state for q = lr (replicated over lg)
#pragma unroll
    for (int i = 0; i < 4; ++i) o[i] = (f32x4){0.f, 0.f, 0.f, 0.f};

    // per wave: 4 K-frags + 4 V-frags (blk = w*4+u in 0..15; LDS slot = blk*512 both)
    auto stage = [&](int kt, int bufi) {
        const int sk0 = kt * 128;
#pragma unroll
        for (int u = 0; u < 4; ++u) {
            const int blk = w * 4 + u;
            const int ct = blk >> 1, kg = blk & 1;       // K frag (ct, kg)
            gload16(Kp + (size_t)(sk0 + ct * 16 + lr) * E_ + kg * 32 + lg * 8,
                    &ldsK[bufi][blk * 512]);
            const int et = blk >> 2, skg = blk & 3;      // V frag (et, skg)
            gload16(Vp + (size_t)(et * 16 + lr) * S_ + sk0 + skg * 32 + lg * 8,
                    &ldsV[bufi][blk * 512]);
        }
    };

    unsigned short* Pw = ldsP + w * 2048;
    const int nkt = (qt >> 1) + 1;

    stage(0, 0);
    if (nkt > 1) stage(1, 1);

    for (int kt = 0; kt < nkt; ++kt) {
        if (kt + 1 < nkt) vm_barrier<8>();
        else              vm_barrier<0>();
        const int cur = kt & 1;
        const unsigned short* Kc = ldsK[cur];
        const unsigned short* Vc = ldsV[cur];

        // S^T = K Q^T (swapped): sc[ct][r] = score[s_k = kt*128+ct*16+lg*4+r][q = lr]
        f32x4 sc[8];
#pragma unroll
        for (int ct = 0; ct < 8; ++ct) sc[ct] = (f32x4){0.f, 0.f, 0.f, 0.f};
#pragma unroll
        for (int ct = 0; ct < 8; ++ct)
#pragma unroll
            for (int kg = 0; kg < 2; ++kg) {
                bh8 kf = *(const bh8*)(Kc + (ct * 2 + kg) * 512 + lane * 8);
                sc[ct] = mfma16(kf, qf[kg], sc[ct]);
            }
        // causal mask: last tile only. off = qt*64 - kt*128 (0 for even qt, 64 for odd)
        if (kt == nkt - 1) {
            const int off = qt * 64 - kt * 128 + w * 16 + lr;
#pragma unroll
            for (int ct = 0; ct < 8; ++ct) {
                const int skl = ct * 16 + lg * 4;
#pragma unroll
                for (int r = 0; r < 4; ++r)
                    if (skl + r > off) sc[ct][r] = -3.0e38f;
            }
        }
        // column (q) max: 31 in-lane fmax + 2 shfl
        float mx = fmaxf(fmaxf(sc[0][0], sc[0][1]), fmaxf(sc[0][2], sc[0][3]));
#pragma unroll
        for (int ct = 1; ct < 8; ++ct)
            mx = fmaxf(mx, fmaxf(fmaxf(sc[ct][0], sc[ct][1]),
                                 fmaxf(sc[ct][2], sc[ct][3])));
        mx = fmaxf(mx, __shfl_xor(mx, 16, 64));
        mx = fmaxf(mx, __shfl_xor(mx, 32, 64));
        // defer-max (T13): rescale only when max grew by > 8 (log2 domain)
        const bool need = mx > m + 8.0f;
        if (__any(need)) {
            const float mn = need ? mx : m;
            const float sf = __builtin_amdgcn_exp2f(m - mn);   // 1.0 when !need
            m = mn;
            l *= sf;
#pragma unroll
            for (int r = 0; r < 4; ++r) {
                const float sfq = __shfl(sf, (lane & 48) + lg * 4 + r, 64);
#pragma unroll
                for (int et = 0; et < 4; ++et) o[et][r] *= sfq;
            }
        }
        // P = exp2(S - m), partial sum in-lane
        float rs = 0.f;
#pragma unroll
        for (int ct = 0; ct < 8; ++ct)
#pragma unroll
            for (int r = 0; r < 4; ++r) {
                float p = __builtin_amdgcn_exp2f(sc[ct][r] - m);
                sc[ct][r] = p;
                rs += p;
            }
        rs += __shfl_xor(rs, 16, 64);
        rs += __shfl_xor(rs, 32, 64);
        l += rs;
        // pack P (cvt_pk) and write A-frag order: 8 x ds_write_b64
#pragma unroll
        for (int ct = 0; ct < 8; ++ct) {
            u32x2 pk = { cvt_pk_bf16(sc[ct][0], sc[ct][1]),
                         cvt_pk_bf16(sc[ct][2], sc[ct][3]) };
            const int addr = (ct >> 1) * 512 +
                             ((((ct & 1) * 2) + (lg >> 1)) * 16 + lr) * 8 + (lg & 1) * 4;
            *(u32x2*)(Pw + addr) = pk;
        }
        // O += P V  (wave-private P; lgkm-ordered, no barrier)
#pragma unroll
        for (int skg = 0; skg < 4; ++skg) {
            bh8 pf = *(const bh8*)(Pw + skg * 512 + lane * 8);
#pragma unroll
            for (int et = 0; et < 4; ++et) {
                bh8 vf = *(const bh8*)(Vc + (et * 4 + skg) * 512 + lane * 8);
                o[et] = mfma16(pf, vf, o[et]);
            }
        }
        post_barrier();
        if (kt + 2 < nkt) stage(kt + 2, cur);
    }
    // epilogue: O/l -> concat layout [B,S,H*64]; l lives at lane with lr = q
    const int b = bh >> 4, hh = bh & 15;
#pragma unroll
    for (int r = 0; r < 4; ++r) {
        const float lq = __shfl(l, (lane & 48) + lg * 4 + r, 64);
        const float inv = 1.0f / lq;
        const int s = qbase + lg * 4 + r;
#pragma unroll
        for (int et = 0; et < 4; ++et)
            ws[OFF_O + ((size_t)(b * S_ + s)) * D_ + hh * E_ + et * 16 + lr] =
                f2bf(o[et][r] * inv);
    }
}

// ---------------- output projection: C[4096,1024] = O * WoT^T ----------------
__global__ __launch_bounds__(256, 3) void k_oproj(const unsigned short* __restrict__ ws,
                                                  const float* __restrict__ bo,
                                                  float* __restrict__ out) {
    const int flat  = blockIdx.x;          // 0..255
    const int idx   = flat >> 3;           // 0..31
    const int stile = (flat & 7) * 4 + (idx & 3);   // 0..31
    const int ntile = idx >> 2;            // 0..7 (128 cols each)
    const unsigned short* A  = ws + OFF_O   + (size_t)stile * 128 * D_;
    const unsigned short* Bw = ws + OFF_WOT + (size_t)ntile * 128 * D_;
    __shared__ __align__(16) unsigned short lds[3 * 8192];
    f32x4 acc[2][8];
#pragma unroll
    for (int i = 0; i < 2; ++i)
#pragma unroll
        for (int j = 0; j < 8; ++j) acc[i][j] = (f32x4){0.f, 0.f, 0.f, 0.f};

    gemm_tile_128x128(A, Bw, lds, acc);

    const int lane = threadIdx.x & 63, w = threadIdx.x >> 6;
    const int lr = lane & 15, lg = lane >> 4;
    const int r0 = stile * 128 + w * 32;
#pragma unroll
    for (int mt = 0; mt < 2; ++mt)
#pragma unroll
        for (int nt = 0; nt < 8; ++nt) {
            const int e = ntile * 128 + nt * 16 + lr;
            const float bia = bo[e];
#pragma unroll
            for (int r = 0; r < 4; ++r)
                out[(size_t)(r0 + mt * 16 + lg * 4 + r) * D_ + e] = acc[mt][nt][r] + bia;
        }
}

extern "C" void kernel_launch(void* const* d_in, const int* in_sizes, int n_in,
                              void* d_out, int out_size, void* d_ws, size_t ws_size,
                              hipStream_t stream) {
    const float* x  = (const float*)d_in[0];
    const float* Wq = (const float*)d_in[1];
    const float* bq = (const float*)d_in[2];
    const float* Wk = (const float*)d_in[3];
    const float* bk = (const float*)d_in[4];
    const float* Wv = (const float*)d_in[5];
    const float* bv = (const float*)d_in[6];
    const float* Wo = (const float*)d_in[7];
    const float* bo = (const float*)d_in[8];
    float* out = (float*)d_out;
    unsigned short* ws = (unsigned short*)d_ws;

    k_prep<<<dim3(5120), 256, 0, stream>>>(x, Wq, Wk, Wv, Wo, ws);
    k_qkv<<<dim3(256), 512, 0, stream>>>(ws, bq, bk, bv);
    k_attn<<<dim3(1024), 256, 0, stream>>>(ws);
    k_oproj<<<dim3(256), 256, 0, stream>>>(ws, bo, out);
}

// Round 20
// 114.051 us; speedup vs baseline: 1.0896x; 1.0037x over previous
//
#include <hip/hip_runtime.h>
#include <stdint.h>

typedef __attribute__((ext_vector_type(8))) short bh8;       // 8 x bf16 (4 VGPR)
typedef __attribute__((ext_vector_type(4))) float f32x4;
typedef __attribute__((ext_vector_type(4))) unsigned short u16x4;
typedef __attribute__((ext_vector_type(8))) unsigned short u16x8;
typedef __attribute__((ext_vector_type(2))) unsigned int u32x2;

#define DEVI static __device__ __forceinline__

constexpr int B_ = 2, S_ = 2048, D_ = 1024, H_ = 16, E_ = 64;

// workspace layout (elements of ushort/bf16)
constexpr size_t OFF_XB  = 0;                              // x as bf16 [B*S, D]
constexpr size_t OFF_WQT = OFF_XB  + (size_t)B_*S_*D_;     // WqT [H, E, D]  } contiguous
constexpr size_t OFF_WKT = OFF_WQT + (size_t)H_*E_*D_;     // WkT [H, E, D]  } = one
constexpr size_t OFF_WVT = OFF_WKT + (size_t)H_*E_*D_;     // WvT [H, E, D]  } [3072,1024]
constexpr size_t OFF_WOT = OFF_WVT + (size_t)H_*E_*D_;     // WoT [D, D]
constexpr size_t OFF_Q   = OFF_WOT + (size_t)D_*D_;        // Q^T [B*H, E, S] (pre-scaled by 0.125*log2e)
constexpr size_t OFF_K   = OFF_Q   + (size_t)B_*H_*S_*E_;  // [B*H, S, E]
constexpr size_t OFF_VT  = OFF_K   + (size_t)B_*H_*S_*E_;  // [B*H, E, S]
constexpr size_t OFF_O   = OFF_VT  + (size_t)B_*H_*S_*E_;  // attn out concat [B*S, D]

DEVI unsigned short f2bf(float f) {
    union { float f; unsigned u; } v; v.f = f;
    unsigned u = v.u;
    return (unsigned short)((u + 0x7fffu + ((u >> 16) & 1u)) >> 16);
}

DEVI unsigned cvt_pk_bf16(float lo, float hi) {   // packs {lo,hi} -> 2 bf16 in one u32
    unsigned r;
    asm("v_cvt_pk_bf16_f32 %0, %1, %2" : "=v"(r) : "v"(lo), "v"(hi));
    return r;
}

DEVI float max3f(float a, float b, float c) {     // clang fuses to v_max3_f32
    return fmaxf(fmaxf(a, b), c);
}

DEVI void gload16(const void* g, void* l) {
    __builtin_amdgcn_global_load_lds(
        (const __attribute__((address_space(1))) unsigned int*)g,
        (__attribute__((address_space(3))) unsigned int*)l, 16, 0, 0);
}

DEVI f32x4 mfma16(bh8 a, bh8 b, f32x4 c) {
    return __builtin_amdgcn_mfma_f32_16x16x32_bf16(a, b, c, 0, 0, 0);
}

// counted-vmcnt barrier: prefetched loads stay in flight across the barrier.
template<int N> DEVI void vm_barrier() {
    asm volatile("s_waitcnt vmcnt(%0)" :: "i"(N) : "memory");
    __builtin_amdgcn_s_barrier();
    __builtin_amdgcn_sched_barrier(0);
}
DEVI void post_barrier() {
    __builtin_amdgcn_sched_barrier(0);
    __builtin_amdgcn_s_barrier();
    __builtin_amdgcn_sched_barrier(0);
}

// ---------------- prep (fused): x -> bf16  AND  weights -> bf16 transposed ----------------
__global__ __launch_bounds__(256) void k_prep(const float* __restrict__ x,
                                              const float* __restrict__ Wq,
                                              const float* __restrict__ Wk,
                                              const float* __restrict__ Wv,
                                              const float* __restrict__ Wo,
                                              unsigned short* __restrict__ ws) {
    const int bid = blockIdx.x;
    const int t   = threadIdx.x;
    if (bid < 4096) {
        const int i = bid * 256 + t;
        const float4 v = ((const float4*)x)[i];
        u16x4 o = { f2bf(v.x), f2bf(v.y), f2bf(v.z), f2bf(v.w) };
        *(u16x4*)(ws + OFF_XB + (size_t)i * 4) = o;
        return;
    }
    const int xi = (bid - 4096) & 255;   // 0..255
    const int z  = (bid - 4096) >> 8;    // 0..3
    __shared__ __align__(16) unsigned short tile[64][72];

    const float* src; unsigned short* dst;
    int inCols, inBase, outBase;
    if (z < 3) {
        src = (z == 0) ? Wq : (z == 1) ? Wk : Wv;
        dst = ws + ((z == 0) ? OFF_WQT : (z == 1) ? OFF_WKT : OFF_WVT);
        inCols = 64;
        inBase = xi * 64 * 64;
        const int h = xi >> 4, dt = xi & 15;
        outBase = h * 65536 + dt * 64;
    } else {
        src = Wo; dst = ws + OFF_WOT;
        inCols = 1024;
        const int et = xi >> 4, dt = xi & 15;
        inBase  = (dt * 64) * 1024 + et * 64;
        outBase = (et * 64) * 1024 + dt * 64;
    }
#pragma unroll
    for (int v = 0; v < 4; ++v) {
        const int flat = v * 256 + t;
        const int i = flat >> 4, j4 = (flat & 15) * 4;
        const float4 val = *(const float4*)(src + inBase + i * inCols + j4);
        tile[i][j4 + 0] = f2bf(val.x);
        tile[i][j4 + 1] = f2bf(val.y);
        tile[i][j4 + 2] = f2bf(val.z);
        tile[i][j4 + 3] = f2bf(val.w);
    }
    __syncthreads();
    const int j = t >> 2, iseg = (t & 3) * 16;
    u16x8 p0, p1;
#pragma unroll
    for (int u = 0; u < 8; ++u) p0[u] = tile[iseg + u][j];
#pragma unroll
    for (int u = 0; u < 8; ++u) p1[u] = tile[iseg + 8 + u][j];
    *(u16x8*)(dst + outBase + (size_t)j * 1024 + iseg)     = p0;
    *(u16x8*)(dst + outBase + (size_t)j * 1024 + iseg + 8) = p1;
}

// ================= qkv 256x192 8-phase machinery =================
// LDS (ushort elems): A dbuf [0, 32768); B dbuf [32768, 57344); scratch [57344, 57856).
DEVI void qkv_stA(const unsigned short* Ap, unsigned short* lds, int kt, int mh, int ks,
                  int lane, int w, int lr, int lg) {
    const int b = kt & 1;
    const int mfrag = (w >> 2) * 8 + mh * 4 + (w & 3);
    gload16(Ap + (size_t)(mfrag * 16 + lr) * D_ + kt * 64 + ks * 32 + lg * 8,
            lds + b * 16384 + (mfrag * 2 + ks) * 512 + lane * 8);
}
// B: 12 nfrags/ks. Waves 0-3 load 2 nfrags; waves 4-7 load 1 + 1 dummy (scratch)
// so every wave issues exactly 2 loads -> per-wave vmcnt FIFO ledger uniform.
DEVI void qkv_stB(const unsigned short* Bp, unsigned short* lds, int kt, int ks,
                  int lane, int w, int lr, int lg) {
    const int b = kt & 1;
    if (w < 4) {
#pragma unroll
        for (int u = 0; u < 2; ++u) {
            const int nfrag = w * 2 + u;
            gload16(Bp + (size_t)(nfrag * 16 + lr) * D_ + kt * 64 + ks * 32 + lg * 8,
                    lds + 32768 + b * 12288 + (nfrag * 2 + ks) * 512 + lane * 8);
        }
    } else {
        const int nfrag = 4 + w;   // 8..11
        gload16(Bp + (size_t)(nfrag * 16 + lr) * D_ + kt * 64 + ks * 32 + lg * 8,
                lds + 32768 + b * 12288 + (nfrag * 2 + ks) * 512 + lane * 8);
        gload16(Bp + (size_t)lr * D_ + lg * 8, lds + 57344 + lane * 8);   // dummy
    }
}
DEVI bh8 qkv_ldA(const unsigned short* lds, int b, int mfrag, int ks, int lane) {
    return *(const bh8*)(lds + b * 16384 + (mfrag * 2 + ks) * 512 + lane * 8);
}
DEVI bh8 qkv_ldB(const unsigned short* lds, int b, int nfrag, int ks, int lane) {
    return *(const bh8*)(lds + 32768 + b * 12288 + (nfrag * 2 + ks) * 512 + lane * 8);
}

// Register-pipelined 8-phase K-tile (R19, kept): each phase's MFMA consumes
// fragments whose ds_reads were issued a full phase earlier.
// vmcnt ledger: steady <11,9,11,12>; kt14 <11,9,8,8>; kt15 <4,1,0,0>.
template<int V0, int V1, int V2, int V3, bool S0, bool S123>
DEVI void qkv_ktile(int kt, const unsigned short* Ap, const unsigned short* Bp,
                    unsigned short* lds, int lane, int w, int lr, int lg,
                    int wm, int wn, f32x4 (&acc)[8][3]) {
    const int b = kt & 1;
    bh8 af0[4], af1[4], af2[4], af3[4], bf0[3], bf1[3];
    // ---- phase 0 ----
    vm_barrier<V0>();
#pragma unroll
    for (int n = 0; n < 3; ++n) bf0[n] = qkv_ldB(lds, b, wn * 3 + n, 0, lane);
#pragma unroll
    for (int q = 0; q < 4; ++q) af0[q] = qkv_ldA(lds, b, wm * 8 + q, 0, lane);
#pragma unroll
    for (int q = 0; q < 4; ++q) af1[q] = qkv_ldA(lds, b, wm * 8 + 4 + q, 0, lane);
    if (S0) qkv_stA(Ap, lds, kt + 1, 1, 1, lane, w, lr, lg);
    __builtin_amdgcn_s_setprio(1);
#pragma unroll
    for (int q = 0; q < 4; ++q)
#pragma unroll
        for (int n = 0; n < 3; ++n) acc[q][n] = mfma16(af0[q], bf0[n], acc[q][n]);
    __builtin_amdgcn_s_setprio(0);
    __builtin_amdgcn_sched_barrier(0);
    // ---- phase 1 ----
    vm_barrier<V1>();
#pragma unroll
    for (int n = 0; n < 3; ++n) bf1[n] = qkv_ldB(lds, b, wn * 3 + n, 1, lane);
#pragma unroll
    for (int q = 0; q < 4; ++q) af2[q] = qkv_ldA(lds, b, wm * 8 + q, 1, lane);
    if (S123) {
        qkv_stA(Ap, lds, kt + 2, 0, 0, lane, w, lr, lg);
        qkv_stB(Bp, lds, kt + 2, 0, lane, w, lr, lg);
    }
    __builtin_amdgcn_s_setprio(1);
#pragma unroll
    for (int q = 0; q < 4; ++q)
#pragma unroll
        for (int n = 0; n < 3; ++n) acc[4 + q][n] = mfma16(af1[q], bf0[n], acc[4 + q][n]);
    __builtin_amdgcn_s_setprio(0);
    __builtin_amdgcn_sched_barrier(0);
    // ---- phase 2 ----
    vm_barrier<V2>();
#pragma unroll
    for (int q = 0; q < 4; ++q) af3[q] = qkv_ldA(lds, b, wm * 8 + 4 + q, 1, lane);
    if (S123) qkv_stA(Ap, lds, kt + 2, 1, 0, lane, w, lr, lg);
    __builtin_amdgcn_s_setprio(1);
#pragma unroll
    for (int q = 0; q < 4; ++q)
#pragma unroll
        for (int n = 0; n < 3; ++n) acc[q][n] = mfma16(af2[q], bf1[n], acc[q][n]);
    __builtin_amdgcn_s_setprio(0);
    __builtin_amdgcn_sched_barrier(0);
    // ---- phase 3 ----
    vm_barrier<V3>();
    if (S123) {
        qkv_stA(Ap, lds, kt + 2, 0, 1, lane, w, lr, lg);
        qkv_stB(Bp, lds, kt + 2, 1, lane, w, lr, lg);
    }
    __builtin_amdgcn_s_setprio(1);
#pragma unroll
    for (int q = 0; q < 4; ++q)
#pragma unroll
        for (int n = 0; n < 3; ++n) acc[4 + q][n] = mfma16(af3[q], bf1[n], acc[4 + q][n]);
    __builtin_amdgcn_s_setprio(0);
    __builtin_amdgcn_sched_barrier(0);
}

// ---------------- fused QKV projection: 256x192 tiles, 8 waves, 8-phase ----------------
__global__ __launch_bounds__(512, 1) void k_qkv(unsigned short* __restrict__ ws,
                                                const float* __restrict__ bq,
                                                const float* __restrict__ bk,
                                                const float* __restrict__ bv) {
    const int flat  = blockIdx.x;                   // 0..255
    const int stile = (flat & 7) * 2 + ((flat >> 3) & 1);   // 0..15 (256 rows each)
    const int ntile = flat >> 4;                    // 0..15 (192 cols each of 3072)
    const unsigned short* Ap = ws + OFF_XB  + (size_t)stile * 256 * D_;
    const unsigned short* Bp = ws + OFF_WQT + (size_t)ntile * 192 * D_;

    __shared__ __align__(16) unsigned short lds[57856];   // 113 KB
    const int tid = threadIdx.x, lane = tid & 63, w = tid >> 6;
    const int lr = lane & 15, lg = lane >> 4;
    const int wm = w >> 2, wn = w & 3;               // wave tile: rows wm*128, cols wn*48

    f32x4 acc[8][3];
#pragma unroll
    for (int i = 0; i < 8; ++i)
#pragma unroll
        for (int j = 0; j < 3; ++j) acc[i][j] = (f32x4){0.f, 0.f, 0.f, 0.f};

    // prologue: kt0 full (8 loads) + kt1 minus A(1,1) (7), steady-state FIFO order
    qkv_stA(Ap, lds, 0, 0, 0, lane, w, lr, lg);
    qkv_stB(Bp, lds, 0, 0, lane, w, lr, lg);
    qkv_stA(Ap, lds, 0, 1, 0, lane, w, lr, lg);
    qkv_stA(Ap, lds, 0, 0, 1, lane, w, lr, lg);
    qkv_stB(Bp, lds, 0, 1, lane, w, lr, lg);
    qkv_stA(Ap, lds, 0, 1, 1, lane, w, lr, lg);
    qkv_stA(Ap, lds, 1, 0, 0, lane, w, lr, lg);
    qkv_stB(Bp, lds, 1, 0, lane, w, lr, lg);
    qkv_stA(Ap, lds, 1, 1, 0, lane, w, lr, lg);
    qkv_stA(Ap, lds, 1, 0, 1, lane, w, lr, lg);
    qkv_stB(Bp, lds, 1, 1, lane, w, lr, lg);

    for (int kt = 0; kt < 14; ++kt)
        qkv_ktile<11, 9, 11, 12, true, true>(kt, Ap, Bp, lds, lane, w, lr, lg, wm, wn, acc);
    qkv_ktile<11, 9, 8, 8, true, false>(14, Ap, Bp, lds, lane, w, lr, lg, wm, wn, acc);
    qkv_ktile<4, 1, 0, 0, false, false>(15, Ap, Bp, lds, lane, w, lr, lg, wm, wn, acc);

    // epilogue: per 16-col group decode (16 | 64 -> never straddles a head)
    const int bb = stile >> 3;                       // batch (256 | 2048, no straddle)
#pragma unroll
    for (int mf = 0; mf < 8; ++mf) {
        const int sl = ((stile * 256 + wm * 128 + mf * 16) & (S_ - 1)) + lg * 4;
#pragma unroll
        for (int nf = 0; nf < 3; ++nf) {
            const int gcol = ntile * 192 + wn * 48 + nf * 16;
            const int mat  = gcol >> 10;
            const int h    = (gcol >> 6) & 15;
            const int e    = (gcol & 63) + lr;
            const int bh   = bb * H_ + h;
            const float bia = ((mat == 0) ? bq : (mat == 1) ? bk : bv)[h * 64 + e];
            if (mat == 0) {        // Q^T [BH][E][S], pre-scaled by 0.125*log2e
                u16x4 pk;
#pragma unroll
                for (int r = 0; r < 4; ++r)
                    pk[r] = f2bf((acc[mf][nf][r] + bia) * 0.1803368801f);
                *(u16x4*)(ws + OFF_Q + ((size_t)(bh * E_ + e)) * S_ + sl) = pk;
            } else if (mat == 2) { // V^T [BH][E][S]
                u16x4 pk;
#pragma unroll
                for (int r = 0; r < 4; ++r) pk[r] = f2bf(acc[mf][nf][r] + bia);
                *(u16x4*)(ws + OFF_VT + ((size_t)(bh * E_ + e)) * S_ + sl) = pk;
            } else {               // K [BH][S][E]
#pragma unroll
                for (int r = 0; r < 4; ++r)
                    ws[OFF_K + ((size_t)bh * S_ + sl + r) * E_ + e] =
                        f2bf(acc[mf][nf][r] + bia);
            }
        }
    }
}

// ---------------- GEMM mainloop: C(128x128) (oproj) ----------------
DEVI void gemm_tile_128x128(const unsigned short* __restrict__ A,
                            const unsigned short* __restrict__ Bw,
                            unsigned short* lds,
                            f32x4 acc[2][8]) {
    const int lane = threadIdx.x & 63;
    const int w    = threadIdx.x >> 6;
    const int lr = lane & 15, lg = lane >> 4;
    const unsigned short* a0 = A  + (size_t)((w * 2 + 0) * 16 + lr) * D_ + lg * 8;
    const unsigned short* a1 = A  + (size_t)((w * 2 + 1) * 16 + lr) * D_ + lg * 8;
    const unsigned short* b0 = Bw + (size_t)((w * 2 + 0) * 16 + lr) * D_ + lg * 8;
    const unsigned short* b1 = Bw + (size_t)((w * 2 + 1) * 16 + lr) * D_ + lg * 8;
    const int oA0 = (w * 2 + 0) * 512, oA1 = (w * 2 + 1) * 512;
    const int oB0 = 4096 + oA0,        oB1 = 4096 + oA1;

    auto stage = [&](int ks, int bufi) {
        unsigned short* base = lds + bufi * 8192;
        gload16(a0 + ks * 32, base + oA0);
        gload16(a1 + ks * 32, base + oA1);
        gload16(b0 + ks * 32, base + oB0);
        gload16(b1 + ks * 32, base + oB1);
    };

    stage(0, 0); stage(1, 1);
    for (int ks = 0; ks < 32; ++ks) {
        if (ks < 31) vm_barrier<4>();
        else         vm_barrier<0>();
        if (ks + 2 < 32) stage(ks + 2, (ks + 2) % 3);
        const unsigned short* base = lds + (ks % 3) * 8192;
        bh8 af0 = *(const bh8*)(base + (w * 2 + 0) * 512 + lane * 8);
        bh8 af1 = *(const bh8*)(base + (w * 2 + 1) * 512 + lane * 8);
#pragma unroll
        for (int nt = 0; nt < 8; ++nt) {
            bh8 bf = *(const bh8*)(base + 4096 + nt * 512 + lane * 8);
            acc[0][nt] = mfma16(af0, bf, acc[0][nt]);
            acc[1][nt] = mfma16(af1, bf, acc[1][nt]);
        }
        __builtin_amdgcn_sched_barrier(0);
    }
}

// ---------------- flash attention (causal), swapped-QK^T, KVBLK=128 ----------------
__global__ __launch_bounds__(256, 2) void k_attn(unsigned short* __restrict__ ws) {
    const int flat = blockIdx.x;          // 0..1023
    const int j    = flat & 31;
    const int qt   = 31 - (flat >> 5);    // heavy tiles first
    const int bh   = (j & 7) * 4 + (j >> 3);
    const int lane = threadIdx.x & 63, w = threadIdx.x >> 6;
    const int lr = lane & 15, lg = lane >> 4;
    const unsigned short* Qp = ws + OFF_Q  + (size_t)bh * E_ * S_;   // Q^T [E][S]
    const unsigned short* Kp = ws + OFF_K  + (size_t)bh * S_ * E_;
    const unsigned short* Vp = ws + OFF_VT + (size_t)bh * E_ * S_;
    __shared__ __align__(16) unsigned short ldsK[2][16 * 512];   // 128x64 K tile, frag order
    __shared__ __align__(16) unsigned short ldsV[2][16 * 512];   // 64x128 V^T tile
    __shared__ __align__(16) unsigned short ldsP[4 * 2048];      // per-wave 16x128 P

    const int qbase = qt * 64 + w * 16;   // this wave's 16 q rows
    bh8 qf[2];
#pragma unroll
    for (int kg = 0; kg < 2; ++kg) {
        bh8 t;
#pragma unroll
        for (int i = 0; i < 8; ++i)
            t[i] = (short)Qp[(size_t)(kg * 32 + lg * 8 + i) * S_ + qbase + lr];
        qf[kg] = t;
    }

    f32x4 o[4];
    float m = -3.0e38f, l = 0.f;    // per-lane online state for q = lr (replicated over lg)
#pragma unroll
    for (int i = 0; i < 4; ++i) o[i] = (f32x4){0.f, 0.f, 0.f, 0.f};

    // per wave: 4 K-frags + 4 V-frags (blk = w*4+u in 0..15; LDS slot = blk*512 both)
    auto stage = [&](int kt, int bufi) {
        const int sk0 = kt * 128;
#pragma unroll
        for (int u = 0; u < 4; ++u) {
            const int blk = w * 4 + u;
            const int ct = blk >> 1, kg = blk & 1;       // K frag (ct, kg)
            gload16(Kp + (size_t)(sk0 + ct * 16 + lr) * E_ + kg * 32 + lg * 8,
                    &ldsK[bufi][blk * 512]);
            const int et = blk >> 2, skg = blk & 3;      // V frag (et, skg)
            gload16(Vp + (size_t)(et * 16 + lr) * S_ + sk0 + skg * 32 + lg * 8,
                    &ldsV[bufi][blk * 512]);
        }
    };

    unsigned short* Pw = ldsP + w * 2048;
    const int nkt = (qt >> 1) + 1;

    stage(0, 0);
    if (nkt > 1) stage(1, 1);

    for (int kt = 0; kt < nkt; ++kt) {
        if (kt + 1 < nkt) vm_barrier<8>();
        else              vm_barrier<0>();
        const int cur = kt & 1;
        const unsigned short* Kc = ldsK[cur];
        const unsigned short* Vc = ldsV[cur];

        // S^T = K Q^T (swapped): sc[ct][r] = score[s_k = kt*128+ct*16+lg*4+r][q = lr]
        f32x4 sc[8];
#pragma unroll
        for (int ct = 0; ct < 8; ++ct) sc[ct] = (f32x4){0.f, 0.f, 0.f, 0.f};
#pragma unroll
        for (int ct = 0; ct < 8; ++ct)
#pragma unroll
            for (int kg = 0; kg < 2; ++kg) {
                bh8 kf = *(const bh8*)(Kc + (ct * 2 + kg) * 512 + lane * 8);
                sc[ct] = mfma16(kf, qf[kg], sc[ct]);
            }
        // causal mask: last tile only. off = qt*64 - kt*128 (0 for even qt, 64 for odd)
        if (kt == nkt - 1) {
            const int off = qt * 64 - kt * 128 + w * 16 + lr;
#pragma unroll
            for (int ct = 0; ct < 8; ++ct) {
                const int skl = ct * 16 + lg * 4;
#pragma unroll
                for (int r = 0; r < 4; ++r)
                    if (skl + r > off) sc[ct][r] = -3.0e38f;
            }
        }
        // column (q) max via v_max3 chains: 2 ops/ct + 2 shfl
        float mx = fmaxf(fmaxf(sc[0][0], sc[0][1]), fmaxf(sc[0][2], sc[0][3]));
#pragma unroll
        for (int ct = 1; ct < 8; ++ct) {
            const float t3 = max3f(sc[ct][0], sc[ct][1], sc[ct][2]);
            mx = max3f(mx, t3, sc[ct][3]);
        }
        mx = fmaxf(mx, __shfl_xor(mx, 16, 64));
        mx = fmaxf(mx, __shfl_xor(mx, 32, 64));
        // defer-max (T13): rescale only when max grew by > 8 (log2 domain)
        const bool need = mx > m + 8.0f;
        if (__any(need)) {
            const float mn = need ? mx : m;
            const float sf = __builtin_amdgcn_exp2f(m - mn);   // 1.0 when !need
            m = mn;
            l *= sf;
#pragma unroll
            for (int r = 0; r < 4; ++r) {
                const float sfq = __shfl(sf, (lane & 48) + lg * 4 + r, 64);
#pragma unroll
                for (int et = 0; et < 4; ++et) o[et][r] *= sfq;
            }
        }
        // P = exp2(S - m), partial sum in-lane
        float rs = 0.f;
#pragma unroll
        for (int ct = 0; ct < 8; ++ct)
#pragma unroll
            for (int r = 0; r < 4; ++r) {
                float p = __builtin_amdgcn_exp2f(sc[ct][r] - m);
                sc[ct][r] = p;
                rs += p;
            }
        rs += __shfl_xor(rs, 16, 64);
        rs += __shfl_xor(rs, 32, 64);
        l += rs;
        // pack P (cvt_pk) and write A-frag order: 8 x ds_write_b64
#pragma unroll
        for (int ct = 0; ct < 8; ++ct) {
            u32x2 pk = { cvt_pk_bf16(sc[ct][0], sc[ct][1]),
                         cvt_pk_bf16(sc[ct][2], sc[ct][3]) };
            const int addr = (ct >> 1) * 512 +
                             ((((ct & 1) * 2) + (lg >> 1)) * 16 + lr) * 8 + (lg & 1) * 4;
            *(u32x2*)(Pw + addr) = pk;
        }
        // O += P V  (wave-private P; lgkm-ordered, no barrier)
#pragma unroll
        for (int skg = 0; skg < 4; ++skg) {
            bh8 pf = *(const bh8*)(Pw + skg * 512 + lane * 8);
#pragma unroll
            for (int et = 0; et < 4; ++et) {
                bh8 vf = *(const bh8*)(Vc + (et * 4 + skg) * 512 + lane * 8);
                o[et] = mfma16(pf, vf, o[et]);
            }
        }
        post_barrier();
        if (kt + 2 < nkt) stage(kt + 2, cur);
    }
    // epilogue: O/l -> concat layout [B,S,H*64]; l lives at lane with lr = q
    const int b = bh >> 4, hh = bh & 15;
#pragma unroll
    for (int r = 0; r < 4; ++r) {
        const float lq = __shfl(l, (lane & 48) + lg * 4 + r, 64);
        const float inv = 1.0f / lq;
        const int s = qbase + lg * 4 + r;
#pragma unroll
        for (int et = 0; et < 4; ++et)
            ws[OFF_O + ((size_t)(b * S_ + s)) * D_ + hh * E_ + et * 16 + lr] =
                f2bf(o[et][r] * inv);
    }
}

// ---------------- output projection: C[4096,1024] = O * WoT^T ----------------
__global__ __launch_bounds__(256, 3) void k_oproj(const unsigned short* __restrict__ ws,
                                                  const float* __restrict__ bo,
                                                  float* __restrict__ out) {
    const int flat  = blockIdx.x;          // 0..255
    const int idx   = flat >> 3;           // 0..31
    const int stile = (flat & 7) * 4 + (idx & 3);   // 0..31
    const int ntile = idx >> 2;            // 0..7 (128 cols each)
    const unsigned short* A  = ws + OFF_O   + (size_t)stile * 128 * D_;
    const unsigned short* Bw = ws + OFF_WOT + (size_t)ntile * 128 * D_;
    __shared__ __align__(16) unsigned short lds[3 * 8192];
    f32x4 acc[2][8];
#pragma unroll
    for (int i = 0; i < 2; ++i)
#pragma unroll
        for (int j = 0; j < 8; ++j) acc[i][j] = (f32x4){0.f, 0.f, 0.f, 0.f};

    gemm_tile_128x128(A, Bw, lds, acc);

    const int lane = threadIdx.x & 63, w = threadIdx.x >> 6;
    const int lr = lane & 15, lg = lane >> 4;
    const int r0 = stile * 128 + w * 32;
#pragma unroll
    for (int mt = 0; mt < 2; ++mt)
#pragma unroll
        for (int nt = 0; nt < 8; ++nt) {
            const int e = ntile * 128 + nt * 16 + lr;
            const float bia = bo[e];
#pragma unroll
            for (int r = 0; r < 4; ++r)
                out[(size_t)(r0 + mt * 16 + lg * 4 + r) * D_ + e] = acc[mt][nt][r] + bia;
        }
}

extern "C" void kernel_launch(void* const* d_in, const int* in_sizes, int n_in,
                              void* d_out, int out_size, void* d_ws, size_t ws_size,
                              hipStream_t stream) {
    const float* x  = (const float*)d_in[0];
    const float* Wq = (const float*)d_in[1];
    const float* bq = (const float*)d_in[2];
    const float* Wk = (const float*)d_in[3];
    const float* bk = (const float*)d_in[4];
    const float* Wv = (const float*)d_in[5];
    const float* bv = (const float*)d_in[6];
    const float* Wo = (const float*)d_in[7];
    const float* bo = (const float*)d_in[8];
    float* out = (float*)d_out;
    unsigned short* ws = (unsigned short*)d_ws;

    k_prep<<<dim3(5120), 256, 0, stream>>>(x, Wq, Wk, Wv, Wo, ws);
    k_qkv<<<dim3(256), 512, 0, stream>>>(ws, bq, bk, bv);
    k_attn<<<dim3(1024), 256, 0, stream>>>(ws);
    k_oproj<<<dim3(256), 256, 0, stream>>>(ws, bo, out);
}